// Round 1
// 1331.047 us; speedup vs baseline: 1.0846x; 1.0846x over previous
//
#include <hip/hip_runtime.h>
#include <cstdint>
#include <cstddef>

// Problem constants
#define SS   64
#define BB   64
#define DM   512
#define NH   8
#define DH   64
#define FF   2048
#define VV   8192
#define LL   6
#define ENCC 2048
#define MR   4096

#define MASK_SENTINEL -3.0e38f

typedef unsigned short u16;
typedef __attribute__((ext_vector_type(8))) short bf16x8;
typedef __attribute__((ext_vector_type(4))) float f32x4;

__device__ __forceinline__ u16 f2b(float f) {
    union { float f; uint32_t u; } c; c.f = f;
    uint32_t u = c.u;
    return (u16)((u + 0x7fffu + ((u >> 16) & 1u)) >> 16);
}
__device__ __forceinline__ float blo(uint32_t p) {
    union { uint32_t u; float f; } c; c.u = p << 16; return c.f;
}
__device__ __forceinline__ float bhi(uint32_t p) {
    union { uint32_t u; float f; } c; c.u = p & 0xffff0000u; return c.f;
}

#define GLL(g, l) __builtin_amdgcn_global_load_lds( \
    (const __attribute__((address_space(1))) void*)(g), \
    (__attribute__((address_space(3))) void*)(l), 16, 0, 0)

// ============ MFMA GEMM, bf16 in/out: C[M,N] = A[M,K] @ BT[N,K]^T ============
// BMT x 128 tile, BK=32, 4 waves. Double-buffered LDS: next k-step's
// global_load_lds is issued BEFORE the current step's ds_read+MFMA, so the
// load latency hides under compute; ONE barrier per k-step (T3 2-phase).
// Dual-source: blocks >= nsplit use the second (A2,BT2,C2) set.
template<int BMT>
__global__ __launch_bounds__(256) void gemm_bf16(
    const u16* __restrict__ A, const u16* __restrict__ BT,
    const float* __restrict__ bias, u16* __restrict__ Cb,
    int K, int ldc, int relu, int nsplit,
    const u16* __restrict__ A2, const u16* __restrict__ BT2,
    u16* __restrict__ C2, int ldc2)
{
    constexpr int WM = BMT / 2;          // wave rows: 64 or 32
    constexpr int AI = WM / 16;          // acc row-frags: 4 or 2
    constexpr int TILE = (BMT + 128) * 32;   // u16 per k-step buffer
    __shared__ __align__(16) u16 smem[2 * TILE];
    const int tid = threadIdx.x;
    const int wave = tid >> 6, lane = tid & 63;

    int bx = blockIdx.x;
    const u16* Ab = A; const u16* Bb = BT; u16* Cp = Cb; int ld = ldc;
    const float* bi = bias; int rl = relu;
    if (bx >= nsplit) { bx -= nsplit; Ab = A2; Bb = BT2; Cp = C2; ld = ldc2; bi = nullptr; rl = 0; }

    const int m0 = blockIdx.y * BMT, n0 = bx * 128;
    const int srow = wave * 16 + (lane >> 2);
    const int scol = (lane & 3) * 8;
    const u16* Ap  = Ab + (size_t)(m0 + srow) * K + scol;
    const u16* Bp  = Bb + (size_t)(n0 + srow) * K + scol;
    const u16* Ap2 = Ap + (size_t)64 * K;
    const u16* Bp2 = Bp + (size_t)64 * K;
    const int aW = wave * 16 * 32;                 // stage dest (A region)
    const int bW = BMT * 32 + wave * 16 * 32;      // stage dest (B region)

    const int wm = wave >> 1, wn = wave & 1;
    const int q = lane >> 4, mr = lane & 15;
    const int aRd = (wm * WM + mr) * 32 + q * 8;
    const int bRd = BMT * 32 + (wn * 64 + mr) * 32 + q * 8;

    f32x4 acc[AI][4];
    const f32x4 z = {0.f, 0.f, 0.f, 0.f};
#pragma unroll
    for (int i = 0; i < AI; i++)
#pragma unroll
        for (int j = 0; j < 4; j++) acc[i][j] = z;

    // prologue: stage k-step 0 into buffer 0
    GLL(Ap, smem + aW);
    if constexpr (BMT == 128) GLL(Ap2, smem + aW + 64 * 32);
    GLL(Bp, smem + bW);
    GLL(Bp2, smem + bW + 64 * 32);
    Ap += 32; Ap2 += 32; Bp += 32; Bp2 += 32;
    __syncthreads();

    int cur = 0;
    for (int k0 = 0; k0 < K; k0 += 32) {
        if (k0 + 32 < K) {                         // prefetch next k-step
            u16* nb = smem + (cur ^ 1) * TILE;
            GLL(Ap, nb + aW);
            if constexpr (BMT == 128) GLL(Ap2, nb + aW + 64 * 32);
            GLL(Bp, nb + bW);
            GLL(Bp2, nb + bW + 64 * 32);
            Ap += 32; Ap2 += 32; Bp += 32; Bp2 += 32;
        }
        const u16* cb = smem + cur * TILE;
        bf16x8 af[AI], bfr[4];
#pragma unroll
        for (int i = 0; i < AI; i++) af[i]  = *(const bf16x8*)(cb + aRd + (size_t)i * 16 * 32);
#pragma unroll
        for (int j = 0; j < 4; j++) bfr[j] = *(const bf16x8*)(cb + bRd + (size_t)j * 16 * 32);
#pragma unroll
        for (int i = 0; i < AI; i++)
#pragma unroll
            for (int j = 0; j < 4; j++)
                acc[i][j] = __builtin_amdgcn_mfma_f32_16x16x32_bf16(af[i], bfr[j], acc[i][j], 0, 0, 0);
        __syncthreads();   // drains vmcnt(0): prefetched loads complete here
        cur ^= 1;
    }

    // ---- epilogue: LDS re-tile to coalesced stores ----
    float* ep = (float*)smem + wave * 1024;        // 16x64 f32, per-wave
    const int lq = lane >> 4, lmr = lane & 15;
    const int colb = n0 + wn * 64 + lmr * 4;
    float4 b4 = make_float4(0.f, 0.f, 0.f, 0.f);
    if (bi) b4 = *(const float4*)(bi + colb);
#pragma unroll
    for (int i = 0; i < AI; i++) {
#pragma unroll
        for (int j = 0; j < 4; j++)
#pragma unroll
            for (int r = 0; r < 4; r++)
                ep[(q * 4 + r) * 64 + j * 16 + mr] = acc[i][j][r];
        __syncthreads();
#pragma unroll
        for (int p = 0; p < 4; p++) {
            const int lr = p * 4 + lq;
            float4 v = *(const float4*)(ep + lr * 64 + lmr * 4);
            v.x += b4.x; v.y += b4.y; v.z += b4.z; v.w += b4.w;
            if (rl) {
                v.x = fmaxf(v.x, 0.f); v.y = fmaxf(v.y, 0.f);
                v.z = fmaxf(v.z, 0.f); v.w = fmaxf(v.w, 0.f);
            }
            uint2 pk;
            pk.x = (uint32_t)f2b(v.x) | ((uint32_t)f2b(v.y) << 16);
            pk.y = (uint32_t)f2b(v.z) | ((uint32_t)f2b(v.w) << 16);
            const int row = m0 + wm * WM + i * 16 + lr;
            *(uint2*)(Cp + (size_t)row * ld + colb) = pk;
        }
        __syncthreads();
    }
}

// ============ logits GEMM: fp32 out + bias + replacement mask ============
__global__ __launch_bounds__(256) void gemm_logits_mfma(
    const u16* __restrict__ A, const u16* __restrict__ BT,
    const float* __restrict__ bias, const int* __restrict__ fo,
    float* __restrict__ C, int K)
{
    constexpr int TILE = 256 * 32;                 // u16 per k-step buffer
    __shared__ __align__(16) u16 smem[2 * TILE];
    const int tid = threadIdx.x;
    const int wave = tid >> 6, lane = tid & 63;
    const int m0 = blockIdx.y * 128, n0 = blockIdx.x * 128;

    const int srow = wave * 16 + (lane >> 2);
    const int scol = (lane & 3) * 8;
    const u16* Ap  = A  + (size_t)(m0 + srow) * K + scol;
    const u16* Bp  = BT + (size_t)(n0 + srow) * K + scol;
    const u16* Ap2 = Ap + (size_t)64 * K;
    const u16* Bp2 = Bp + (size_t)64 * K;
    const int aW = wave * 16 * 32;
    const int bW = 128 * 32 + wave * 16 * 32;

    const int wm = wave >> 1, wn = wave & 1;
    const int q = lane >> 4, mr = lane & 15;
    const int aRd = (wm * 64 + mr) * 32 + q * 8;
    const int bRd = 128 * 32 + (wn * 64 + mr) * 32 + q * 8;

    f32x4 acc[4][4];
    const f32x4 z = {0.f, 0.f, 0.f, 0.f};
#pragma unroll
    for (int i = 0; i < 4; i++)
#pragma unroll
        for (int j = 0; j < 4; j++) acc[i][j] = z;

    GLL(Ap,  smem + aW);
    GLL(Ap2, smem + aW + 64 * 32);
    GLL(Bp,  smem + bW);
    GLL(Bp2, smem + bW + 64 * 32);
    Ap += 32; Ap2 += 32; Bp += 32; Bp2 += 32;
    __syncthreads();

    int cur = 0;
    for (int k0 = 0; k0 < K; k0 += 32) {
        if (k0 + 32 < K) {
            u16* nb = smem + (cur ^ 1) * TILE;
            GLL(Ap,  nb + aW);
            GLL(Ap2, nb + aW + 64 * 32);
            GLL(Bp,  nb + bW);
            GLL(Bp2, nb + bW + 64 * 32);
            Ap += 32; Ap2 += 32; Bp += 32; Bp2 += 32;
        }
        const u16* cb = smem + cur * TILE;
        bf16x8 af[4], bfr[4];
#pragma unroll
        for (int i = 0; i < 4; i++) af[i]  = *(const bf16x8*)(cb + aRd + (size_t)i * 16 * 32);
#pragma unroll
        for (int j = 0; j < 4; j++) bfr[j] = *(const bf16x8*)(cb + bRd + (size_t)j * 16 * 32);
#pragma unroll
        for (int i = 0; i < 4; i++)
#pragma unroll
            for (int j = 0; j < 4; j++)
                acc[i][j] = __builtin_amdgcn_mfma_f32_16x16x32_bf16(af[i], bfr[j], acc[i][j], 0, 0, 0);
        __syncthreads();
        cur ^= 1;
    }

    float* ep = (float*)smem + wave * 1024;
    const int lq = lane >> 4, lmr = lane & 15;
    const int colb = n0 + wn * 64 + lmr * 4;
    const float4 b4 = *(const float4*)(bias + colb);
#pragma unroll
    for (int i = 0; i < 4; i++) {
#pragma unroll
        for (int j = 0; j < 4; j++)
#pragma unroll
            for (int r = 0; r < 4; r++)
                ep[(q * 4 + r) * 64 + j * 16 + mr] = acc[i][j][r];
        __syncthreads();
#pragma unroll
        for (int p = 0; p < 4; p++) {
            const int lr = p * 4 + lq;
            const int row = m0 + wm * 64 + i * 16 + lr;
            const int b = row >> 6, pos = row & 63;
            float4 v = *(const float4*)(ep + lr * 64 + lmr * 4);
            const int4 f4 = *(const int4*)(fo + (size_t)b * VV + colb);
            v.x = (f4.x <= pos) ? MASK_SENTINEL : v.x + b4.x;
            v.y = (f4.y <= pos) ? MASK_SENTINEL : v.y + b4.y;
            v.z = (f4.z <= pos) ? MASK_SENTINEL : v.z + b4.z;
            v.w = (f4.w <= pos) ? MASK_SENTINEL : v.w + b4.w;
            *(float4*)(C + (size_t)row * VV + colb) = v;
        }
        __syncthreads();
    }
}

// ============ batched 512x512 transpose+convert of the 8 per-layer weights ============
struct TPB {
    const float* s[8];
    u16* d[8];
    long dz[8];
};

__global__ __launch_bounds__(256) void transpose8_kernel(TPB t)
{
    __shared__ float tl[32][33];
    const int zz = blockIdx.z;          // m*6 + l
    const int m = zz / 6, l = zz - m * 6;
    const float* in = t.s[m] + (size_t)l * 262144;
    u16* out = t.d[m] + (size_t)l * t.dz[m];
    const int r0 = blockIdx.y * 32, c0 = blockIdx.x * 32;
    const int tx = threadIdx.x & 31, ty = threadIdx.x >> 5;
#pragma unroll
    for (int i = 0; i < 4; i++)
        tl[ty + 8 * i][tx] = in[(size_t)(r0 + ty + 8 * i) * 512 + c0 + tx];
    __syncthreads();
#pragma unroll
    for (int i = 0; i < 4; i++)
        out[(size_t)(c0 + ty + 8 * i) * 512 + r0 + tx] = f2b(tl[tx][ty + 8 * i]);
}

// ============ generic transpose + fp32->bf16: in[R][C] -> out[C][R] ============
__global__ __launch_bounds__(256) void transpose_bf16_kernel(
    const float* __restrict__ in, u16* __restrict__ out,
    int R, int C, size_t in_z, size_t out_z)
{
    __shared__ float tl[32][33];
    in  += (size_t)blockIdx.z * in_z;
    out += (size_t)blockIdx.z * out_z;
    const int r0 = blockIdx.y * 32, c0 = blockIdx.x * 32;
    const int tx = threadIdx.x & 31, ty = threadIdx.x >> 5;
#pragma unroll
    for (int i = 0; i < 4; i++)
        tl[ty + 8 * i][tx] = in[(size_t)(r0 + ty + 8 * i) * C + c0 + tx];
    __syncthreads();
#pragma unroll
    for (int i = 0; i < 4; i++)
        out[(size_t)(c0 + ty + 8 * i) * R + r0 + tx] = f2b(tl[tx][ty + 8 * i]);
}

// ============ fp32 -> bf16 convert ============
__global__ __launch_bounds__(256) void convert_bf16_kernel(
    const float* __restrict__ in, u16* __restrict__ out)
{
    const int idx = blockIdx.x * 256 + threadIdx.x;
    float4 v = *reinterpret_cast<const float4*>(in + (size_t)idx * 4);
    uint2 p;
    p.x = (uint32_t)f2b(v.x) | ((uint32_t)f2b(v.y) << 16);
    p.y = (uint32_t)f2b(v.z) | ((uint32_t)f2b(v.w) << 16);
    *reinterpret_cast<uint2*>(out + (size_t)idx * 4) = p;
}

// ============ attention: bf16 q/k/v in, bf16 out; one block per (b,h) ============
__global__ __launch_bounds__(256) void attn_kernel(
    const u16* __restrict__ qg, int qld,
    const u16* __restrict__ kg, const u16* __restrict__ vg, int kvld,
    u16* __restrict__ og, int causal)
{
    __shared__ float qs[SS][68];
    __shared__ float ks[SS][68];
    __shared__ float vs[SS][68];
    __shared__ float red[SS][8];
    float (*ps)[68] = qs;

    const int tid = threadIdx.x;
    const int bh = blockIdx.x;
    const int b = bh >> 3, h = bh & 7;
    const size_t qbase = (size_t)b * SS * qld + (size_t)h * DH;
    const size_t kbase = (size_t)b * SS * kvld + (size_t)h * DH;
    const size_t obase = (size_t)b * SS * DM + (size_t)h * DH;

#pragma unroll
    for (int it = 0; it < 4; it++) {
        int idx = tid + 256 * it;          // 0..1023
        int s = idx >> 4;
        int d4 = (idx & 15) << 2;
        uint2 a = *(const uint2*)(qg + qbase + (size_t)s * qld + d4);
        qs[s][d4 + 0] = blo(a.x); qs[s][d4 + 1] = bhi(a.x);
        qs[s][d4 + 2] = blo(a.y); qs[s][d4 + 3] = bhi(a.y);
        uint2 c = *(const uint2*)(kg + kbase + (size_t)s * kvld + d4);
        ks[s][d4 + 0] = blo(c.x); ks[s][d4 + 1] = bhi(c.x);
        ks[s][d4 + 2] = blo(c.y); ks[s][d4 + 3] = bhi(c.y);
        uint2 e = *(const uint2*)(vg + kbase + (size_t)s * kvld + d4);
        vs[s][d4 + 0] = blo(e.x); vs[s][d4 + 1] = bhi(e.x);
        vs[s][d4 + 2] = blo(e.y); vs[s][d4 + 3] = bhi(e.y);
    }
    __syncthreads();

    const int r = tid >> 2, c = tid & 3;

    float sc[16];
#pragma unroll
    for (int jj = 0; jj < 16; jj++) sc[jj] = 0.f;
    for (int d4 = 0; d4 < 64; d4 += 4) {
        float4 qv = *reinterpret_cast<const float4*>(&qs[r][d4]);
#pragma unroll
        for (int jj = 0; jj < 16; jj++) {
            int j = jj * 4 + c;
            float4 kv = *reinterpret_cast<const float4*>(&ks[j][d4]);
            sc[jj] += qv.x * kv.x + qv.y * kv.y + qv.z * kv.z + qv.w * kv.w;
        }
    }
    float mx = -1e30f;
#pragma unroll
    for (int jj = 0; jj < 16; jj++) {
        int j = jj * 4 + c;
        float s_ = sc[jj] * 0.125f;
        if (causal && j > r) s_ = -1e9f;
        sc[jj] = s_;
        mx = fmaxf(mx, s_);
    }
    red[r][c] = mx;
    __syncthreads();
    float m = fmaxf(fmaxf(red[r][0], red[r][1]), fmaxf(red[r][2], red[r][3]));
    float sum = 0.f;
#pragma unroll
    for (int jj = 0; jj < 16; jj++) {
        float p = expf(sc[jj] - m);
        sc[jj] = p;
        sum += p;
    }
    red[r][4 + c] = sum;
    __syncthreads();
    float tot = red[r][4] + red[r][5] + red[r][6] + red[r][7];
    float inv = 1.f / tot;
#pragma unroll
    for (int jj = 0; jj < 16; jj++) ps[r][jj * 4 + c] = sc[jj] * inv;
    __syncthreads();

    float acc[16];
#pragma unroll
    for (int i = 0; i < 16; i++) acc[i] = 0.f;
    for (int j = 0; j < 64; j++) {
        float pj = ps[r][j];
#pragma unroll
        for (int dd = 0; dd < 4; dd++) {
            float4 vv = *reinterpret_cast<const float4*>(&vs[j][c * 16 + dd * 4]);
            acc[dd * 4 + 0] += pj * vv.x;
            acc[dd * 4 + 1] += pj * vv.y;
            acc[dd * 4 + 2] += pj * vv.z;
            acc[dd * 4 + 3] += pj * vv.w;
        }
    }
#pragma unroll
    for (int dd = 0; dd < 4; dd++) {
        uint2 p;
        p.x = (uint32_t)f2b(acc[dd * 4 + 0]) | ((uint32_t)f2b(acc[dd * 4 + 1]) << 16);
        p.y = (uint32_t)f2b(acc[dd * 4 + 2]) | ((uint32_t)f2b(acc[dd * 4 + 3]) << 16);
        *reinterpret_cast<uint2*>(&og[obase + (size_t)r * DM + c * 16 + dd * 4]) = p;
    }
}

// ============ residual add + layernorm; x fp32, proj bf16; writes fp32 + bf16 ============
__global__ __launch_bounds__(256) void add_ln_kernel(
    const float* __restrict__ x, const u16* __restrict__ a,
    const float* __restrict__ g, const float* __restrict__ be,
    float* __restrict__ y, u16* __restrict__ yb)
{
    const int wave = threadIdx.x >> 6, lane = threadIdx.x & 63;
    const int row = blockIdx.x * 4 + wave;
    const float* xr = x + (size_t)row * DM;
    const u16* ar = a + (size_t)row * DM;
    float* yr = y + (size_t)row * DM;
    u16* ybr = yb + (size_t)row * DM;

    float vbuf[8];
    float sum = 0.f, sq = 0.f;
#pragma unroll
    for (int i = 0; i < 2; i++) {
        int d = lane * 8 + i * 4;
        float4 xv = *reinterpret_cast<const float4*>(&xr[d]);
        uint2 av = *(const uint2*)(ar + d);
        float a0 = blo(av.x), a1 = bhi(av.x), a2 = blo(av.y), a3 = bhi(av.y);
        float v0 = xv.x + a0, v1 = xv.y + a1, v2 = xv.z + a2, v3 = xv.w + a3;
        vbuf[i * 4 + 0] = v0; vbuf[i * 4 + 1] = v1;
        vbuf[i * 4 + 2] = v2; vbuf[i * 4 + 3] = v3;
        sum += v0 + v1 + v2 + v3;
        sq += v0 * v0 + v1 * v1 + v2 * v2 + v3 * v3;
    }
#pragma unroll
    for (int off = 32; off; off >>= 1) {
        sum += __shfl_xor(sum, off, 64);
        sq  += __shfl_xor(sq, off, 64);
    }
    float mean = sum * (1.f / 512.f);
    float var = sq * (1.f / 512.f) - mean * mean;
    float rs = rsqrtf(var + 1e-3f);
#pragma unroll
    for (int i = 0; i < 2; i++) {
        int d = lane * 8 + i * 4;
        float4 gv = *reinterpret_cast<const float4*>(&g[d]);
        float4 bv = *reinterpret_cast<const float4*>(&be[d]);
        float4 ov;
        ov.x = (vbuf[i * 4 + 0] - mean) * rs * gv.x + bv.x;
        ov.y = (vbuf[i * 4 + 1] - mean) * rs * gv.y + bv.y;
        ov.z = (vbuf[i * 4 + 2] - mean) * rs * gv.z + bv.z;
        ov.w = (vbuf[i * 4 + 3] - mean) * rs * gv.w + bv.w;
        *reinterpret_cast<float4*>(&yr[d]) = ov;
        uint2 p;
        p.x = (uint32_t)f2b(ov.x) | ((uint32_t)f2b(ov.y) << 16);
        p.y = (uint32_t)f2b(ov.z) | ((uint32_t)f2b(ov.w) << 16);
        *reinterpret_cast<uint2*>(&ybr[d]) = p;
    }
}

// ============ embedding; writes fp32 + bf16 ============
__global__ __launch_bounds__(256) void embed_kernel(
    const int* __restrict__ targets, const float* __restrict__ tok,
    const float* __restrict__ pos, float* __restrict__ x, u16* __restrict__ xb)
{
    int idx = blockIdx.x * 256 + threadIdx.x;
    int row = idx >> 7;
    int d4 = (idx & 127) << 2;
    int s = row & 63;
    int t = targets[row];
    float4 tv = *reinterpret_cast<const float4*>(&tok[(size_t)t * DM + d4]);
    float4 pv = *reinterpret_cast<const float4*>(&pos[(size_t)s * DM + d4]);
    float4 ov = make_float4(tv.x + pv.x, tv.y + pv.y, tv.z + pv.z, tv.w + pv.w);
    *reinterpret_cast<float4*>(&x[(size_t)row * DM + d4]) = ov;
    uint2 p;
    p.x = (uint32_t)f2b(ov.x) | ((uint32_t)f2b(ov.y) << 16);
    p.y = (uint32_t)f2b(ov.z) | ((uint32_t)f2b(ov.w) << 16);
    *reinterpret_cast<uint2*>(&xb[(size_t)row * DM + d4]) = p;
}

// ============ replacement-mask first-occurrence ============
__global__ __launch_bounds__(256) void init_fo_kernel(int* __restrict__ fo)
{
    fo[blockIdx.x * 256 + threadIdx.x] = SS;
}

__global__ __launch_bounds__(256) void scatter_fo_kernel(
    const int* __restrict__ targets, int* __restrict__ fo)
{
    int i = blockIdx.x * 256 + threadIdx.x;
    int t = targets[i];
    if (t != 0) atomicMin(&fo[(size_t)(i >> 6) * VV + t], i & 63);
}

// ============ launch ============
extern "C" void kernel_launch(void* const* d_in, const int* in_sizes, int n_in,
                              void* d_out, int out_size, void* d_ws, size_t ws_size,
                              hipStream_t stream)
{
    const float* enc_feat = (const float*)d_in[0];
    const int*   targets  = (const int*)d_in[1];
    const float* conv_w   = (const float*)d_in[2];
    const float* conv_b   = (const float*)d_in[3];
    const float* tok_emb  = (const float*)d_in[4];
    const float* pos_emb  = (const float*)d_in[5];
    const float* Wq_s     = (const float*)d_in[6];
    const float* Wk_s     = (const float*)d_in[7];
    const float* Wv_s     = (const float*)d_in[8];
    const float* Wo_s     = (const float*)d_in[9];
    const float* Wq_c     = (const float*)d_in[10];
    const float* Wk_c     = (const float*)d_in[11];
    const float* Wv_c     = (const float*)d_in[12];
    const float* Wo_c     = (const float*)d_in[13];
    const float* W1       = (const float*)d_in[14];
    const float* fb1      = (const float*)d_in[15];
    const float* W2       = (const float*)d_in[16];
    const float* fb2      = (const float*)d_in[17];
    const float* g1       = (const float*)d_in[18];
    const float* be1      = (const float*)d_in[19];
    const float* g2       = (const float*)d_in[20];
    const float* be2      = (const float*)d_in[21];
    const float* g3       = (const float*)d_in[22];
    const float* be3      = (const float*)d_in[23];
    const float* Wout     = (const float*)d_in[24];
    const float* bout     = (const float*)d_in[25];
    float* out = (float*)d_out;

    // ---- workspace layout (u16 units from base; ~160 MB total, ws = 512 MB) ----
    u16* base = (u16*)d_ws;
    float* x   = (float*)d_ws;                 // 4096x512 f32 (residual)
    u16* xb    = base + 4194304;               // 4096x512 bf16
    u16* projb = base + 6291456;               // 4096x512 bf16
    u16* qcb   = base + 8388608;               // 4096x512 bf16 (cross Q)
    u16* attnb = base + 10485760;              // 4096x512 bf16
    u16* encb  = base + 12582912;              // 4096x512 bf16
    u16* big   = base + 14680064;              // 4096x2048 bf16 (qkv | ffn-h | enc_feat)
    int* fo    = (int*)(base + 23068672);      // 64x8192 int
    u16* qkvT  = base + 24117248;              // [6][1536][512]
    u16* woTs  = base + 28835840;              // [6][512][512]
    u16* wqTc  = base + 30408704;              // [6][512][512]
    u16* kvTc  = base + 31981568;              // [6][1024][512] (contiguous => [6144][512])
    u16* woTc  = base + 35127296;              // [6][512][512]
    u16* w1T   = base + 36700160;              // [6][2048][512]
    u16* w2T   = base + 42991616;              // [6][512][2048]
    u16* cvT   = base + 49283072;              // [512][2048]
    u16* woutT = base + 50331648;              // [8192][512]
    u16* kvAll = base + 54525952;              // [4096][6144] bf16: all-layer cross K|V

    const dim3 blk(256);

    // ---- mask precompute + embedding + enc_feat conversion ----
    init_fo_kernel<<<dim3(BB * VV / 256), blk, 0, stream>>>(fo);
    scatter_fo_kernel<<<dim3(MR / 256), blk, 0, stream>>>(targets, fo);
    embed_kernel<<<dim3(MR * DM / 4 / 256), blk, 0, stream>>>(targets, tok_emb, pos_emb, x, xb);
    convert_bf16_kernel<<<dim3(MR * ENCC / 4 / 256), blk, 0, stream>>>(enc_feat, big);

    // ---- weight transpose+convert ----
    TPB tp;
    tp.s[0] = Wq_s; tp.d[0] = qkvT;          tp.dz[0] = 786432;
    tp.s[1] = Wk_s; tp.d[1] = qkvT + 262144; tp.dz[1] = 786432;
    tp.s[2] = Wv_s; tp.d[2] = qkvT + 524288; tp.dz[2] = 786432;
    tp.s[3] = Wo_s; tp.d[3] = woTs;          tp.dz[3] = 262144;
    tp.s[4] = Wq_c; tp.d[4] = wqTc;          tp.dz[4] = 262144;
    tp.s[5] = Wk_c; tp.d[5] = kvTc;          tp.dz[5] = 524288;
    tp.s[6] = Wv_c; tp.d[6] = kvTc + 262144; tp.dz[6] = 524288;
    tp.s[7] = Wo_c; tp.d[7] = woTc;          tp.dz[7] = 262144;
    transpose8_kernel<<<dim3(16, 16, 48), blk, 0, stream>>>(tp);
    transpose_bf16_kernel<<<dim3(64, 16, 6), blk, 0, stream>>>(W1, w1T, 512, 2048, 1048576, 1048576);
    transpose_bf16_kernel<<<dim3(16, 64, 6), blk, 0, stream>>>(W2, w2T, 2048, 512, 1048576, 1048576);
    transpose_bf16_kernel<<<dim3(16, 64, 1), blk, 0, stream>>>(conv_w, cvT, 2048, 512, 0, 0);
    transpose_bf16_kernel<<<dim3(256, 16, 1), blk, 0, stream>>>(Wout, woutT, 512, 8192, 0, 0);

    // ---- encoder projection: big(enc_feat bf16) @ cvT + conv_b -> encb ----
    gemm_bf16<64><<<dim3(4, 64), blk, 0, stream>>>(big, cvT, conv_b, encb, ENCC, DM, 0, 9999,
                                                   nullptr, nullptr, nullptr, 0);

    // ---- hoisted cross-attention K|V for ALL layers: encb @ kvTc^T -> kvAll ----
    // kvTc is [6][1024][512] contiguous == [6144][512]; output ld = 6144.
    gemm_bf16<128><<<dim3(48, 32), blk, 0, stream>>>(encb, kvTc, nullptr, kvAll, DM, 6144, 0, 9999,
                                                     nullptr, nullptr, nullptr, 0);

    for (int l = 0; l < LL; l++) {
        // self-attention: fused QKV -> big[4096][1536]
        gemm_bf16<128><<<dim3(12, 32), blk, 0, stream>>>(xb, qkvT + (size_t)l * 786432, nullptr,
                                                         big, DM, 1536, 0, 9999,
                                                         nullptr, nullptr, nullptr, 0);
        attn_kernel<<<dim3(BB * NH), blk, 0, stream>>>(big, 1536, big + 512, big + 1024, 1536, attnb, 1);
        gemm_bf16<64><<<dim3(4, 64), blk, 0, stream>>>(attnb, woTs + (size_t)l * 262144, nullptr,
                                                       projb, DM, DM, 0, 9999,
                                                       nullptr, nullptr, nullptr, 0);
        add_ln_kernel<<<dim3(MR / 4), blk, 0, stream>>>(x, projb, g1 + l * DM, be1 + l * DM, x, xb);
        // cross-attention: Q projection only (KV hoisted to kvAll)
        gemm_bf16<64><<<dim3(4, 64), blk, 0, stream>>>(xb, wqTc + (size_t)l * 262144, nullptr,
                                                       qcb, DM, DM, 0, 9999,
                                                       nullptr, nullptr, nullptr, 0);
        attn_kernel<<<dim3(BB * NH), blk, 0, stream>>>(qcb, 512,
                                                       kvAll + (size_t)l * 1024,
                                                       kvAll + (size_t)l * 1024 + 512, 6144, attnb, 0);
        gemm_bf16<64><<<dim3(4, 64), blk, 0, stream>>>(attnb, woTc + (size_t)l * 262144, nullptr,
                                                       projb, DM, DM, 0, 9999,
                                                       nullptr, nullptr, nullptr, 0);
        add_ln_kernel<<<dim3(MR / 4), blk, 0, stream>>>(x, projb, g2 + l * DM, be2 + l * DM, x, xb);
        // FFN
        gemm_bf16<128><<<dim3(16, 32), blk, 0, stream>>>(xb, w1T + (size_t)l * 1048576,
                                                         fb1 + (size_t)l * FF, big, DM, FF, 1, 9999,
                                                         nullptr, nullptr, nullptr, 0);
        gemm_bf16<64><<<dim3(4, 64), blk, 0, stream>>>(big, w2T + (size_t)l * 1048576,
                                                       fb2 + (size_t)l * DM, projb, FF, DM, 0, 9999,
                                                       nullptr, nullptr, nullptr, 0);
        add_ln_kernel<<<dim3(MR / 4), blk, 0, stream>>>(x, projb, g3 + l * DM, be3 + l * DM, x, xb);
    }

    // logits + bias + replacement mask
    gemm_logits_mfma<<<dim3(64, 32), blk, 0, stream>>>(xb, woutT, bout, fo, out, DM);
}

// Round 2
// 1239.778 us; speedup vs baseline: 1.1645x; 1.0736x over previous
//
#include <hip/hip_runtime.h>
#include <cstdint>
#include <cstddef>

// Problem constants
#define SS   64
#define BB   64
#define DM   512
#define NH   8
#define DH   64
#define FF   2048
#define VV   8192
#define LL   6
#define ENCC 2048
#define MR   4096

#define MASK_SENTINEL -3.0e38f

typedef unsigned short u16;
typedef __attribute__((ext_vector_type(8))) short bf16x8;
typedef __attribute__((ext_vector_type(4))) float f32x4;

__device__ __forceinline__ u16 f2b(float f) {
    union { float f; uint32_t u; } c; c.f = f;
    uint32_t u = c.u;
    return (u16)((u + 0x7fffu + ((u >> 16) & 1u)) >> 16);
}
__device__ __forceinline__ float blo(uint32_t p) {
    union { uint32_t u; float f; } c; c.u = p << 16; return c.f;
}
__device__ __forceinline__ float bhi(uint32_t p) {
    union { uint32_t u; float f; } c; c.u = p & 0xffff0000u; return c.f;
}

#define GLL(g, l) __builtin_amdgcn_global_load_lds( \
    (const __attribute__((address_space(1))) void*)(g), \
    (__attribute__((address_space(3))) void*)(l), 16, 0, 0)

#define WAITV2 asm volatile("s_waitcnt vmcnt(2)" ::: "memory")
#define WAITV3 asm volatile("s_waitcnt vmcnt(3)" ::: "memory")
#define WAITV4 asm volatile("s_waitcnt vmcnt(4)" ::: "memory")
#define WAITV0 asm volatile("s_waitcnt vmcnt(0)" ::: "memory")
#define WAITL0 asm volatile("s_waitcnt lgkmcnt(0)" ::: "memory")

// ============ MFMA GEMM, bf16 in/out: C[M,N] = A[M,K] @ BT[N,K]^T ============
// BMT x BNT tile, BK=32, 4 waves. 3-buffer LDS, depth-2 prefetch with
// counted s_waitcnt vmcnt(G) + raw s_barrier (T3+T4): prefetched loads get
// ~2 full steps to land and the barrier never drains them. Per step:
//   vmcnt(G) -> s_barrier -> ds_read frags -> lgkmcnt(0) (publishes "my
//   reads of this buffer are done" to the next barrier, making the k+2
//   overwrite safe) -> issue k+2 stage -> MFMA. Last step peeled (vmcnt 0).
template<int BMT, int BNT>
__global__ __launch_bounds__(256) void gemm_bf16(
    const u16* __restrict__ A, const u16* __restrict__ BT,
    const float* __restrict__ bias, u16* __restrict__ Cb,
    int K, int ldc, int relu)
{
    constexpr int WNW = (BNT == 128) ? 2 : 1;   // waves along N
    constexpr int WMW = 4 / WNW;                // waves along M
    constexpr int WM = BMT / WMW;               // rows per wave
    constexpr int AI = WM / 16;                 // acc row-frags
    constexpr int AG = BMT / 64;                // A GLLs per wave per step
    constexpr int BG = BNT / 64;                // B GLLs per wave per step
    constexpr int G  = AG + BG;
    constexpr int TILE = (BMT + BNT) * 32;      // u16 per k-step buffer
    __shared__ __align__(16) u16 smem[3 * TILE];
    const int tid = threadIdx.x;
    const int wave = tid >> 6, lane = tid & 63;

    const int m0 = blockIdx.y * BMT, n0 = blockIdx.x * BNT;
    const int srow = wave * 16 + (lane >> 2);
    const int scol = (lane & 3) * 8;
    const u16* Ap  = A  + (size_t)(m0 + srow) * K + scol;
    const u16* Bp  = BT + (size_t)(n0 + srow) * K + scol;
    const u16* Ap2 = Ap + (size_t)64 * K;
    const u16* Bp2 = Bp + (size_t)64 * K;
    const int aW = wave * 16 * 32;              // stage dest (A region)
    const int bW = BMT * 32 + wave * 16 * 32;   // stage dest (B region)

    const int wm = (BNT == 128) ? (wave >> 1) : wave;
    const int wn = (BNT == 128) ? (wave & 1) : 0;
    const int q = lane >> 4, mr = lane & 15;
    const int aRd = (wm * WM + mr) * 32 + q * 8;
    const int bRd = BMT * 32 + (wn * 64 + mr) * 32 + q * 8;

    f32x4 acc[AI][4];
    const f32x4 z = {0.f, 0.f, 0.f, 0.f};
#pragma unroll
    for (int i = 0; i < AI; i++)
#pragma unroll
        for (int j = 0; j < 4; j++) acc[i][j] = z;

#define STAGE(buf) do { \
        GLL(Ap, (buf) + aW); \
        if constexpr (AG == 2) GLL(Ap2, (buf) + aW + 64 * 32); \
        GLL(Bp, (buf) + bW); \
        if constexpr (BG == 2) GLL(Bp2, (buf) + bW + 64 * 32); \
        Ap += 32; Bp += 32; \
        if constexpr (AG == 2) Ap2 += 32; \
        if constexpr (BG == 2) Bp2 += 32; \
    } while (0)

    u16* rd = smem;
    u16* md = smem + TILE;
    u16* pf = smem + 2 * TILE;
    STAGE(rd);
    STAGE(md);
    const int NS = K >> 5;

    for (int k = 0; k < NS - 1; k++) {
        if constexpr (G == 2) WAITV2;
        else if constexpr (G == 3) WAITV3;
        else WAITV4;
        __builtin_amdgcn_s_barrier();
        bf16x8 af[AI], bfr[4];
#pragma unroll
        for (int i = 0; i < AI; i++) af[i]  = *(const bf16x8*)(rd + aRd + i * 16 * 32);
#pragma unroll
        for (int j = 0; j < 4; j++) bfr[j] = *(const bf16x8*)(rd + bRd + j * 16 * 32);
        WAITL0;
        __builtin_amdgcn_sched_barrier(0);
        if (k + 2 < NS) STAGE(pf);
#pragma unroll
        for (int i = 0; i < AI; i++)
#pragma unroll
            for (int j = 0; j < 4; j++)
                acc[i][j] = __builtin_amdgcn_mfma_f32_16x16x32_bf16(af[i], bfr[j], acc[i][j], 0, 0, 0);
        u16* t = rd; rd = md; md = pf; pf = t;
    }
    // peeled last step
    WAITV0;
    __builtin_amdgcn_s_barrier();
    {
        bf16x8 af[AI], bfr[4];
#pragma unroll
        for (int i = 0; i < AI; i++) af[i]  = *(const bf16x8*)(rd + aRd + i * 16 * 32);
#pragma unroll
        for (int j = 0; j < 4; j++) bfr[j] = *(const bf16x8*)(rd + bRd + j * 16 * 32);
#pragma unroll
        for (int i = 0; i < AI; i++)
#pragma unroll
            for (int j = 0; j < 4; j++)
                acc[i][j] = __builtin_amdgcn_mfma_f32_16x16x32_bf16(af[i], bfr[j], acc[i][j], 0, 0, 0);
    }
    __syncthreads();
#undef STAGE

    // ---- epilogue: LDS re-tile to coalesced stores ----
    float* ep = (float*)smem + wave * 1024;        // 16x64 f32, per-wave
    const int lq = lane >> 4, lmr = lane & 15;
    const int colb = n0 + wn * 64 + lmr * 4;
    float4 b4 = make_float4(0.f, 0.f, 0.f, 0.f);
    if (bias) b4 = *(const float4*)(bias + colb);
#pragma unroll
    for (int i = 0; i < AI; i++) {
#pragma unroll
        for (int j = 0; j < 4; j++)
#pragma unroll
            for (int r = 0; r < 4; r++)
                ep[(q * 4 + r) * 64 + j * 16 + mr] = acc[i][j][r];
        __syncthreads();
#pragma unroll
        for (int p = 0; p < 4; p++) {
            const int lr = p * 4 + lq;
            float4 v = *(const float4*)(ep + lr * 64 + lmr * 4);
            v.x += b4.x; v.y += b4.y; v.z += b4.z; v.w += b4.w;
            if (relu) {
                v.x = fmaxf(v.x, 0.f); v.y = fmaxf(v.y, 0.f);
                v.z = fmaxf(v.z, 0.f); v.w = fmaxf(v.w, 0.f);
            }
            uint2 pk;
            pk.x = (uint32_t)f2b(v.x) | ((uint32_t)f2b(v.y) << 16);
            pk.y = (uint32_t)f2b(v.z) | ((uint32_t)f2b(v.w) << 16);
            const int row = m0 + wm * WM + i * 16 + lr;
            *(uint2*)(Cb + (size_t)row * ldc + colb) = pk;
        }
        __syncthreads();
    }
}

// ============ logits GEMM: fp32 out + bias + replacement mask ============
// 128x128 tile, same 3-buffer depth-2 counted-vmcnt pipeline (G=4).
__global__ __launch_bounds__(256) void gemm_logits_mfma(
    const u16* __restrict__ A, const u16* __restrict__ BT,
    const float* __restrict__ bias, const int* __restrict__ fo,
    float* __restrict__ C, int K)
{
    constexpr int TILE = 256 * 32;
    __shared__ __align__(16) u16 smem[3 * TILE];
    const int tid = threadIdx.x;
    const int wave = tid >> 6, lane = tid & 63;
    const int m0 = blockIdx.y * 128, n0 = blockIdx.x * 128;

    const int srow = wave * 16 + (lane >> 2);
    const int scol = (lane & 3) * 8;
    const u16* Ap  = A  + (size_t)(m0 + srow) * K + scol;
    const u16* Bp  = BT + (size_t)(n0 + srow) * K + scol;
    const u16* Ap2 = Ap + (size_t)64 * K;
    const u16* Bp2 = Bp + (size_t)64 * K;
    const int aW = wave * 16 * 32;
    const int bW = 128 * 32 + wave * 16 * 32;

    const int wm = wave >> 1, wn = wave & 1;
    const int q = lane >> 4, mr = lane & 15;
    const int aRd = (wm * 64 + mr) * 32 + q * 8;
    const int bRd = 128 * 32 + (wn * 64 + mr) * 32 + q * 8;

    f32x4 acc[4][4];
    const f32x4 z = {0.f, 0.f, 0.f, 0.f};
#pragma unroll
    for (int i = 0; i < 4; i++)
#pragma unroll
        for (int j = 0; j < 4; j++) acc[i][j] = z;

#define STAGE4(buf) do { \
        GLL(Ap,  (buf) + aW); \
        GLL(Ap2, (buf) + aW + 64 * 32); \
        GLL(Bp,  (buf) + bW); \
        GLL(Bp2, (buf) + bW + 64 * 32); \
        Ap += 32; Ap2 += 32; Bp += 32; Bp2 += 32; \
    } while (0)

    u16* rd = smem;
    u16* md = smem + TILE;
    u16* pf = smem + 2 * TILE;
    STAGE4(rd);
    STAGE4(md);
    const int NS = K >> 5;

    for (int k = 0; k < NS - 1; k++) {
        WAITV4;
        __builtin_amdgcn_s_barrier();
        bf16x8 af[4], bfr[4];
#pragma unroll
        for (int i = 0; i < 4; i++) af[i]  = *(const bf16x8*)(rd + aRd + i * 16 * 32);
#pragma unroll
        for (int j = 0; j < 4; j++) bfr[j] = *(const bf16x8*)(rd + bRd + j * 16 * 32);
        WAITL0;
        __builtin_amdgcn_sched_barrier(0);
        if (k + 2 < NS) STAGE4(pf);
#pragma unroll
        for (int i = 0; i < 4; i++)
#pragma unroll
            for (int j = 0; j < 4; j++)
                acc[i][j] = __builtin_amdgcn_mfma_f32_16x16x32_bf16(af[i], bfr[j], acc[i][j], 0, 0, 0);
        u16* t = rd; rd = md; md = pf; pf = t;
    }
    WAITV0;
    __builtin_amdgcn_s_barrier();
    {
        bf16x8 af[4], bfr[4];
#pragma unroll
        for (int i = 0; i < 4; i++) af[i]  = *(const bf16x8*)(rd + aRd + i * 16 * 32);
#pragma unroll
        for (int j = 0; j < 4; j++) bfr[j] = *(const bf16x8*)(rd + bRd + j * 16 * 32);
#pragma unroll
        for (int i = 0; i < 4; i++)
#pragma unroll
            for (int j = 0; j < 4; j++)
                acc[i][j] = __builtin_amdgcn_mfma_f32_16x16x32_bf16(af[i], bfr[j], acc[i][j], 0, 0, 0);
    }
    __syncthreads();
#undef STAGE4

    float* ep = (float*)smem + wave * 1024;
    const int lq = lane >> 4, lmr = lane & 15;
    const int colb = n0 + wn * 64 + lmr * 4;
    const float4 b4 = *(const float4*)(bias + colb);
#pragma unroll
    for (int i = 0; i < 4; i++) {
#pragma unroll
        for (int j = 0; j < 4; j++)
#pragma unroll
            for (int r = 0; r < 4; r++)
                ep[(q * 4 + r) * 64 + j * 16 + mr] = acc[i][j][r];
        __syncthreads();
#pragma unroll
        for (int p = 0; p < 4; p++) {
            const int lr = p * 4 + lq;
            const int row = m0 + wm * 64 + i * 16 + lr;
            const int b = row >> 6, pos = row & 63;
            float4 v = *(const float4*)(ep + lr * 64 + lmr * 4);
            const int4 f4 = *(const int4*)(fo + (size_t)b * VV + colb);
            v.x = (f4.x <= pos) ? MASK_SENTINEL : v.x + b4.x;
            v.y = (f4.y <= pos) ? MASK_SENTINEL : v.y + b4.y;
            v.z = (f4.z <= pos) ? MASK_SENTINEL : v.z + b4.z;
            v.w = (f4.w <= pos) ? MASK_SENTINEL : v.w + b4.w;
            *(float4*)(C + (size_t)row * VV + colb) = v;
        }
        __syncthreads();
    }
}

// ============ batched 512x512 transpose+convert of the 8 per-layer weights ============
struct TPB {
    const float* s[8];
    u16* d[8];
    long dz[8];
};

__global__ __launch_bounds__(256) void transpose8_kernel(TPB t)
{
    __shared__ float tl[32][33];
    const int zz = blockIdx.z;          // m*6 + l
    const int m = zz / 6, l = zz - m * 6;
    const float* in = t.s[m] + (size_t)l * 262144;
    u16* out = t.d[m] + (size_t)l * t.dz[m];
    const int r0 = blockIdx.y * 32, c0 = blockIdx.x * 32;
    const int tx = threadIdx.x & 31, ty = threadIdx.x >> 5;
#pragma unroll
    for (int i = 0; i < 4; i++)
        tl[ty + 8 * i][tx] = in[(size_t)(r0 + ty + 8 * i) * 512 + c0 + tx];
    __syncthreads();
#pragma unroll
    for (int i = 0; i < 4; i++)
        out[(size_t)(c0 + ty + 8 * i) * 512 + r0 + tx] = f2b(tl[tx][ty + 8 * i]);
}

// ============ generic transpose + fp32->bf16: in[R][C] -> out[C][R] ============
__global__ __launch_bounds__(256) void transpose_bf16_kernel(
    const float* __restrict__ in, u16* __restrict__ out,
    int R, int C, size_t in_z, size_t out_z)
{
    __shared__ float tl[32][33];
    in  += (size_t)blockIdx.z * in_z;
    out += (size_t)blockIdx.z * out_z;
    const int r0 = blockIdx.y * 32, c0 = blockIdx.x * 32;
    const int tx = threadIdx.x & 31, ty = threadIdx.x >> 5;
#pragma unroll
    for (int i = 0; i < 4; i++)
        tl[ty + 8 * i][tx] = in[(size_t)(r0 + ty + 8 * i) * C + c0 + tx];
    __syncthreads();
#pragma unroll
    for (int i = 0; i < 4; i++)
        out[(size_t)(c0 + ty + 8 * i) * R + r0 + tx] = f2b(tl[tx][ty + 8 * i]);
}

// ============ fp32 -> bf16 convert ============
__global__ __launch_bounds__(256) void convert_bf16_kernel(
    const float* __restrict__ in, u16* __restrict__ out)
{
    const int idx = blockIdx.x * 256 + threadIdx.x;
    float4 v = *reinterpret_cast<const float4*>(in + (size_t)idx * 4);
    uint2 p;
    p.x = (uint32_t)f2b(v.x) | ((uint32_t)f2b(v.y) << 16);
    p.y = (uint32_t)f2b(v.z) | ((uint32_t)f2b(v.w) << 16);
    *reinterpret_cast<uint2*>(out + (size_t)idx * 4) = p;
}

// ============ attention: bf16 q/k/v in, bf16 out; one block per (b,h) ============
__global__ __launch_bounds__(256) void attn_kernel(
    const u16* __restrict__ qg, int qld,
    const u16* __restrict__ kg, const u16* __restrict__ vg, int kvld,
    u16* __restrict__ og, int causal)
{
    __shared__ float qs[SS][68];
    __shared__ float ks[SS][68];
    __shared__ float vs[SS][68];
    __shared__ float red[SS][8];
    float (*ps)[68] = qs;

    const int tid = threadIdx.x;
    const int bh = blockIdx.x;
    const int b = bh >> 3, h = bh & 7;
    const size_t qbase = (size_t)b * SS * qld + (size_t)h * DH;
    const size_t kbase = (size_t)b * SS * kvld + (size_t)h * DH;
    const size_t obase = (size_t)b * SS * DM + (size_t)h * DH;

#pragma unroll
    for (int it = 0; it < 4; it++) {
        int idx = tid + 256 * it;          // 0..1023
        int s = idx >> 4;
        int d4 = (idx & 15) << 2;
        uint2 a = *(const uint2*)(qg + qbase + (size_t)s * qld + d4);
        qs[s][d4 + 0] = blo(a.x); qs[s][d4 + 1] = bhi(a.x);
        qs[s][d4 + 2] = blo(a.y); qs[s][d4 + 3] = bhi(a.y);
        uint2 c = *(const uint2*)(kg + kbase + (size_t)s * kvld + d4);
        ks[s][d4 + 0] = blo(c.x); ks[s][d4 + 1] = bhi(c.x);
        ks[s][d4 + 2] = blo(c.y); ks[s][d4 + 3] = bhi(c.y);
        uint2 e = *(const uint2*)(vg + kbase + (size_t)s * kvld + d4);
        vs[s][d4 + 0] = blo(e.x); vs[s][d4 + 1] = bhi(e.x);
        vs[s][d4 + 2] = blo(e.y); vs[s][d4 + 3] = bhi(e.y);
    }
    __syncthreads();

    const int r = tid >> 2, c = tid & 3;

    float sc[16];
#pragma unroll
    for (int jj = 0; jj < 16; jj++) sc[jj] = 0.f;
    for (int d4 = 0; d4 < 64; d4 += 4) {
        float4 qv = *reinterpret_cast<const float4*>(&qs[r][d4]);
#pragma unroll
        for (int jj = 0; jj < 16; jj++) {
            int j = jj * 4 + c;
            float4 kv = *reinterpret_cast<const float4*>(&ks[j][d4]);
            sc[jj] += qv.x * kv.x + qv.y * kv.y + qv.z * kv.z + qv.w * kv.w;
        }
    }
    float mx = -1e30f;
#pragma unroll
    for (int jj = 0; jj < 16; jj++) {
        int j = jj * 4 + c;
        float s_ = sc[jj] * 0.125f;
        if (causal && j > r) s_ = -1e9f;
        sc[jj] = s_;
        mx = fmaxf(mx, s_);
    }
    red[r][c] = mx;
    __syncthreads();
    float m = fmaxf(fmaxf(red[r][0], red[r][1]), fmaxf(red[r][2], red[r][3]));
    float sum = 0.f;
#pragma unroll
    for (int jj = 0; jj < 16; jj++) {
        float p = expf(sc[jj] - m);
        sc[jj] = p;
        sum += p;
    }
    red[r][4 + c] = sum;
    __syncthreads();
    float tot = red[r][4] + red[r][5] + red[r][6] + red[r][7];
    float inv = 1.f / tot;
#pragma unroll
    for (int jj = 0; jj < 16; jj++) ps[r][jj * 4 + c] = sc[jj] * inv;
    __syncthreads();

    float acc[16];
#pragma unroll
    for (int i = 0; i < 16; i++) acc[i] = 0.f;
    for (int j = 0; j < 64; j++) {
        float pj = ps[r][j];
#pragma unroll
        for (int dd = 0; dd < 4; dd++) {
            float4 vv = *reinterpret_cast<const float4*>(&vs[j][c * 16 + dd * 4]);
            acc[dd * 4 + 0] += pj * vv.x;
            acc[dd * 4 + 1] += pj * vv.y;
            acc[dd * 4 + 2] += pj * vv.z;
            acc[dd * 4 + 3] += pj * vv.w;
        }
    }
#pragma unroll
    for (int dd = 0; dd < 4; dd++) {
        uint2 p;
        p.x = (uint32_t)f2b(acc[dd * 4 + 0]) | ((uint32_t)f2b(acc[dd * 4 + 1]) << 16);
        p.y = (uint32_t)f2b(acc[dd * 4 + 2]) | ((uint32_t)f2b(acc[dd * 4 + 3]) << 16);
        *reinterpret_cast<uint2*>(&og[obase + (size_t)r * DM + c * 16 + dd * 4]) = p;
    }
}

// ============ residual add + layernorm; x fp32, proj bf16; writes fp32 + bf16 ============
__global__ __launch_bounds__(256) void add_ln_kernel(
    const float* __restrict__ x, const u16* __restrict__ a,
    const float* __restrict__ g, const float* __restrict__ be,
    float* __restrict__ y, u16* __restrict__ yb)
{
    const int wave = threadIdx.x >> 6, lane = threadIdx.x & 63;
    const int row = blockIdx.x * 4 + wave;
    const float* xr = x + (size_t)row * DM;
    const u16* ar = a + (size_t)row * DM;
    float* yr = y + (size_t)row * DM;
    u16* ybr = yb + (size_t)row * DM;

    float vbuf[8];
    float sum = 0.f, sq = 0.f;
#pragma unroll
    for (int i = 0; i < 2; i++) {
        int d = lane * 8 + i * 4;
        float4 xv = *reinterpret_cast<const float4*>(&xr[d]);
        uint2 av = *(const uint2*)(ar + d);
        float a0 = blo(av.x), a1 = bhi(av.x), a2 = blo(av.y), a3 = bhi(av.y);
        float v0 = xv.x + a0, v1 = xv.y + a1, v2 = xv.z + a2, v3 = xv.w + a3;
        vbuf[i * 4 + 0] = v0; vbuf[i * 4 + 1] = v1;
        vbuf[i * 4 + 2] = v2; vbuf[i * 4 + 3] = v3;
        sum += v0 + v1 + v2 + v3;
        sq += v0 * v0 + v1 * v1 + v2 * v2 + v3 * v3;
    }
#pragma unroll
    for (int off = 32; off; off >>= 1) {
        sum += __shfl_xor(sum, off, 64);
        sq  += __shfl_xor(sq, off, 64);
    }
    float mean = sum * (1.f / 512.f);
    float var = sq * (1.f / 512.f) - mean * mean;
    float rs = rsqrtf(var + 1e-3f);
#pragma unroll
    for (int i = 0; i < 2; i++) {
        int d = lane * 8 + i * 4;
        float4 gv = *reinterpret_cast<const float4*>(&g[d]);
        float4 bv = *reinterpret_cast<const float4*>(&be[d]);
        float4 ov;
        ov.x = (vbuf[i * 4 + 0] - mean) * rs * gv.x + bv.x;
        ov.y = (vbuf[i * 4 + 1] - mean) * rs * gv.y + bv.y;
        ov.z = (vbuf[i * 4 + 2] - mean) * rs * gv.z + bv.z;
        ov.w = (vbuf[i * 4 + 3] - mean) * rs * gv.w + bv.w;
        *reinterpret_cast<float4*>(&yr[d]) = ov;
        uint2 p;
        p.x = (uint32_t)f2b(ov.x) | ((uint32_t)f2b(ov.y) << 16);
        p.y = (uint32_t)f2b(ov.z) | ((uint32_t)f2b(ov.w) << 16);
        *reinterpret_cast<uint2*>(&ybr[d]) = p;
    }
}

// ============ embedding; writes fp32 + bf16 ============
__global__ __launch_bounds__(256) void embed_kernel(
    const int* __restrict__ targets, const float* __restrict__ tok,
    const float* __restrict__ pos, float* __restrict__ x, u16* __restrict__ xb)
{
    int idx = blockIdx.x * 256 + threadIdx.x;
    int row = idx >> 7;
    int d4 = (idx & 127) << 2;
    int s = row & 63;
    int t = targets[row];
    float4 tv = *reinterpret_cast<const float4*>(&tok[(size_t)t * DM + d4]);
    float4 pv = *reinterpret_cast<const float4*>(&pos[(size_t)s * DM + d4]);
    float4 ov = make_float4(tv.x + pv.x, tv.y + pv.y, tv.z + pv.z, tv.w + pv.w);
    *reinterpret_cast<float4*>(&x[(size_t)row * DM + d4]) = ov;
    uint2 p;
    p.x = (uint32_t)f2b(ov.x) | ((uint32_t)f2b(ov.y) << 16);
    p.y = (uint32_t)f2b(ov.z) | ((uint32_t)f2b(ov.w) << 16);
    *reinterpret_cast<uint2*>(&xb[(size_t)row * DM + d4]) = p;
}

// ============ replacement-mask first-occurrence ============
__global__ __launch_bounds__(256) void init_fo_kernel(int* __restrict__ fo)
{
    fo[blockIdx.x * 256 + threadIdx.x] = SS;
}

__global__ __launch_bounds__(256) void scatter_fo_kernel(
    const int* __restrict__ targets, int* __restrict__ fo)
{
    int i = blockIdx.x * 256 + threadIdx.x;
    int t = targets[i];
    if (t != 0) atomicMin(&fo[(size_t)(i >> 6) * VV + t], i & 63);
}

// ============ launch ============
extern "C" void kernel_launch(void* const* d_in, const int* in_sizes, int n_in,
                              void* d_out, int out_size, void* d_ws, size_t ws_size,
                              hipStream_t stream)
{
    const float* enc_feat = (const float*)d_in[0];
    const int*   targets  = (const int*)d_in[1];
    const float* conv_w   = (const float*)d_in[2];
    const float* conv_b   = (const float*)d_in[3];
    const float* tok_emb  = (const float*)d_in[4];
    const float* pos_emb  = (const float*)d_in[5];
    const float* Wq_s     = (const float*)d_in[6];
    const float* Wk_s     = (const float*)d_in[7];
    const float* Wv_s     = (const float*)d_in[8];
    const float* Wo_s     = (const float*)d_in[9];
    const float* Wq_c     = (const float*)d_in[10];
    const float* Wk_c     = (const float*)d_in[11];
    const float* Wv_c     = (const float*)d_in[12];
    const float* Wo_c     = (const float*)d_in[13];
    const float* W1       = (const float*)d_in[14];
    const float* fb1      = (const float*)d_in[15];
    const float* W2       = (const float*)d_in[16];
    const float* fb2      = (const float*)d_in[17];
    const float* g1       = (const float*)d_in[18];
    const float* be1      = (const float*)d_in[19];
    const float* g2       = (const float*)d_in[20];
    const float* be2      = (const float*)d_in[21];
    const float* g3       = (const float*)d_in[22];
    const float* be3      = (const float*)d_in[23];
    const float* Wout     = (const float*)d_in[24];
    const float* bout     = (const float*)d_in[25];
    float* out = (float*)d_out;

    // ---- workspace layout (u16 units from base; ~160 MB total, ws = 512 MB) ----
    u16* base = (u16*)d_ws;
    float* x   = (float*)d_ws;                 // 4096x512 f32 (residual)
    u16* xb    = base + 4194304;               // 4096x512 bf16
    u16* projb = base + 6291456;               // 4096x512 bf16
    u16* qcb   = base + 8388608;               // 4096x512 bf16 (cross Q)
    u16* attnb = base + 10485760;              // 4096x512 bf16
    u16* encb  = base + 12582912;              // 4096x512 bf16
    u16* big   = base + 14680064;              // 4096x2048 bf16 (qkv | ffn-h | enc_feat)
    int* fo    = (int*)(base + 23068672);      // 64x8192 int
    u16* qkvT  = base + 24117248;              // [6][1536][512]
    u16* woTs  = base + 28835840;              // [6][512][512]
    u16* wqTc  = base + 30408704;              // [6][512][512]
    u16* kvTc  = base + 31981568;              // [6][1024][512] (contiguous => [6144][512])
    u16* woTc  = base + 35127296;              // [6][512][512]
    u16* w1T   = base + 36700160;              // [6][2048][512]
    u16* w2T   = base + 42991616;              // [6][512][2048]
    u16* cvT   = base + 49283072;              // [512][2048]
    u16* woutT = base + 50331648;              // [8192][512]
    u16* kvAll = base + 54525952;              // [4096][6144] bf16: all-layer cross K|V

    const dim3 blk(256);

    // ---- mask precompute + embedding + enc_feat conversion ----
    init_fo_kernel<<<dim3(BB * VV / 256), blk, 0, stream>>>(fo);
    scatter_fo_kernel<<<dim3(MR / 256), blk, 0, stream>>>(targets, fo);
    embed_kernel<<<dim3(MR * DM / 4 / 256), blk, 0, stream>>>(targets, tok_emb, pos_emb, x, xb);
    convert_bf16_kernel<<<dim3(MR * ENCC / 4 / 256), blk, 0, stream>>>(enc_feat, big);

    // ---- weight transpose+convert ----
    TPB tp;
    tp.s[0] = Wq_s; tp.d[0] = qkvT;          tp.dz[0] = 786432;
    tp.s[1] = Wk_s; tp.d[1] = qkvT + 262144; tp.dz[1] = 786432;
    tp.s[2] = Wv_s; tp.d[2] = qkvT + 524288; tp.dz[2] = 786432;
    tp.s[3] = Wo_s; tp.d[3] = woTs;          tp.dz[3] = 262144;
    tp.s[4] = Wq_c; tp.d[4] = wqTc;          tp.dz[4] = 262144;
    tp.s[5] = Wk_c; tp.d[5] = kvTc;          tp.dz[5] = 524288;
    tp.s[6] = Wv_c; tp.d[6] = kvTc + 262144; tp.dz[6] = 524288;
    tp.s[7] = Wo_c; tp.d[7] = woTc;          tp.dz[7] = 262144;
    transpose8_kernel<<<dim3(16, 16, 48), blk, 0, stream>>>(tp);
    transpose_bf16_kernel<<<dim3(64, 16, 6), blk, 0, stream>>>(W1, w1T, 512, 2048, 1048576, 1048576);
    transpose_bf16_kernel<<<dim3(16, 64, 6), blk, 0, stream>>>(W2, w2T, 2048, 512, 1048576, 1048576);
    transpose_bf16_kernel<<<dim3(16, 64, 1), blk, 0, stream>>>(conv_w, cvT, 2048, 512, 0, 0);
    transpose_bf16_kernel<<<dim3(256, 16, 1), blk, 0, stream>>>(Wout, woutT, 512, 8192, 0, 0);

    // ---- encoder projection: big(enc_feat bf16) @ cvT + conv_b -> encb ----
    gemm_bf16<64, 64><<<dim3(8, 64), blk, 0, stream>>>(big, cvT, conv_b, encb, ENCC, DM, 0);

    // ---- hoisted cross-attention K|V for ALL layers: encb @ kvTc^T -> kvAll ----
    // kvTc is [6][1024][512] contiguous == [6144][512]; output ld = 6144.
    gemm_bf16<64, 128><<<dim3(48, 64), blk, 0, stream>>>(encb, kvTc, nullptr, kvAll, DM, 6144, 0);

    for (int l = 0; l < LL; l++) {
        // self-attention: fused QKV -> big[4096][1536]
        gemm_bf16<64, 128><<<dim3(12, 64), blk, 0, stream>>>(xb, qkvT + (size_t)l * 786432, nullptr,
                                                             big, DM, 1536, 0);
        attn_kernel<<<dim3(BB * NH), blk, 0, stream>>>(big, 1536, big + 512, big + 1024, 1536, attnb, 1);
        gemm_bf16<64, 64><<<dim3(8, 64), blk, 0, stream>>>(attnb, woTs + (size_t)l * 262144, nullptr,
                                                           projb, DM, DM, 0);
        add_ln_kernel<<<dim3(MR / 4), blk, 0, stream>>>(x, projb, g1 + l * DM, be1 + l * DM, x, xb);
        // cross-attention: Q projection only (KV hoisted to kvAll)
        gemm_bf16<64, 64><<<dim3(8, 64), blk, 0, stream>>>(xb, wqTc + (size_t)l * 262144, nullptr,
                                                           qcb, DM, DM, 0);
        attn_kernel<<<dim3(BB * NH), blk, 0, stream>>>(qcb, 512,
                                                       kvAll + (size_t)l * 1024,
                                                       kvAll + (size_t)l * 1024 + 512, 6144, attnb, 0);
        gemm_bf16<64, 64><<<dim3(8, 64), blk, 0, stream>>>(attnb, woTc + (size_t)l * 262144, nullptr,
                                                           projb, DM, DM, 0);
        add_ln_kernel<<<dim3(MR / 4), blk, 0, stream>>>(x, projb, g2 + l * DM, be2 + l * DM, x, xb);
        // FFN
        gemm_bf16<64, 128><<<dim3(16, 64), blk, 0, stream>>>(xb, w1T + (size_t)l * 1048576,
                                                             fb1 + (size_t)l * FF, big, DM, FF, 1);
        gemm_bf16<64, 64><<<dim3(8, 64), blk, 0, stream>>>(big, w2T + (size_t)l * 1048576,
                                                           fb2 + (size_t)l * DM, projb, FF, DM, 0);
        add_ln_kernel<<<dim3(MR / 4), blk, 0, stream>>>(x, projb, g3 + l * DM, be3 + l * DM, x, xb);
    }

    // logits + bias + replacement mask
    gemm_logits_mfma<<<dim3(64, 32), blk, 0, stream>>>(xb, woutT, bout, fo, out, DM);
}

// Round 3
// 1228.525 us; speedup vs baseline: 1.1751x; 1.0092x over previous
//
#include <hip/hip_runtime.h>
#include <cstdint>
#include <cstddef>

// Problem constants
#define SS   64
#define BB   64
#define DM   512
#define NH   8
#define DH   64
#define FF   2048
#define VV   8192
#define LL   6
#define ENCC 2048
#define MR   4096

#define MASK_SENTINEL -3.0e38f

typedef unsigned short u16;
typedef __attribute__((ext_vector_type(8))) short bf16x8;
typedef __attribute__((ext_vector_type(4))) float f32x4;

__device__ __forceinline__ u16 f2b(float f) {
    union { float f; uint32_t u; } c; c.f = f;
    uint32_t u = c.u;
    return (u16)((u + 0x7fffu + ((u >> 16) & 1u)) >> 16);
}
__device__ __forceinline__ float blo(uint32_t p) {
    union { uint32_t u; float f; } c; c.u = p << 16; return c.f;
}
__device__ __forceinline__ float bhi(uint32_t p) {
    union { uint32_t u; float f; } c; c.u = p & 0xffff0000u; return c.f;
}

#define GLL(g, l) __builtin_amdgcn_global_load_lds( \
    (const __attribute__((address_space(1))) void*)(g), \
    (__attribute__((address_space(3))) void*)(l), 16, 0, 0)

#define WAITV0 asm volatile("s_waitcnt vmcnt(0)" ::: "memory")
#define WAITV4 asm volatile("s_waitcnt vmcnt(4)" ::: "memory")
#define WAITL0 asm volatile("s_waitcnt lgkmcnt(0)" ::: "memory")

// ============ MFMA GEMM, bf16 in/out: C[M,N] = A[M,K] @ BT[N,K]^T ============
// BMT x BNT tile, BK=64, 4 waves. 3-buffer LDS, depth-2 prefetch with counted
// s_waitcnt vmcnt(G) + raw s_barrier. LDS tile rows are 128 B (8 x 16 B
// chunks) XOR-swizzled: chunk c of row r lives at c ^ (r&7). Since
// global_load_lds writes linearly, the swizzle is applied by pre-swizzling
// the per-lane GLOBAL source column (same involution on both sides).
// Fragment ds_read_b128 are then 2-way (conflict-free) instead of 8-16 way.
template<int BMT, int BNT>
__global__ __launch_bounds__(256) void gemm_bf16(
    const u16* __restrict__ A, const u16* __restrict__ BT,
    const float* __restrict__ bias, u16* __restrict__ Cb,
    int K, int ldc, int relu)
{
    constexpr int WNW = (BNT == 128) ? 2 : 1;   // waves along N
    constexpr int WMW = 4 / WNW;                // waves along M
    constexpr int WM  = BMT / WMW;              // rows per wave
    constexpr int AI  = WM / 16;                // acc row-frags
    constexpr int AG  = BMT / 32;               // A GLLs per wave (8 rows each)
    constexpr int BG  = BNT / 32;               // B GLLs per wave
    constexpr int G   = AG + BG;
    constexpr int TILE = (BMT + BNT) * 64;      // u16 per k-step buffer (BK=64)
    __shared__ __align__(16) u16 smem[3 * TILE];
    const int tid = threadIdx.x;
    const int wave = tid >> 6, lane = tid & 63;

    const int m0 = blockIdx.y * BMT, n0 = blockIdx.x * BNT;

    // staging: each GLL covers 8 rows x 128 B; lane -> (row=lane>>3, chunk=lane&7)
    const int r8 = lane >> 3;                   // row within 8-row group (== row&7)
    const int sc = ((lane & 7) ^ r8) * 8;       // pre-swizzled source col (u16)
    const u16* Ap = A  + (size_t)(m0 + wave * (AG * 8) + r8) * K + sc;
    const u16* Bp = BT + (size_t)(n0 + wave * (BG * 8) + r8) * K + sc;
    const int aW = wave * (AG * 8) * 64;        // LDS dest base (A region, u16)
    const int bW = BMT * 64 + wave * (BG * 8) * 64;

    const int wm = (BNT == 128) ? (wave >> 1) : wave;
    const int wn = (BNT == 128) ? (wave & 1) : 0;
    const int q = lane >> 4, mr = lane & 15;
    const int wmR = wm * WM;
    // swizzled chunk offsets for the two k-halves (u16 units)
    const int sw0 = ((q)     ^ (mr & 7)) * 8;
    const int sw1 = ((4 + q) ^ (mr & 7)) * 8;

    f32x4 acc[AI][4];
    const f32x4 z = {0.f, 0.f, 0.f, 0.f};
#pragma unroll
    for (int i = 0; i < AI; i++)
#pragma unroll
        for (int j = 0; j < 4; j++) acc[i][j] = z;

    auto STAGE = [&](u16* buf) {
#pragma unroll
        for (int i = 0; i < AG; i++)
            GLL(Ap + (size_t)(i * 8) * K, buf + aW + i * 8 * 64);
#pragma unroll
        for (int i = 0; i < BG; i++)
            GLL(Bp + (size_t)(i * 8) * K, buf + bW + i * 8 * 64);
        Ap += 64; Bp += 64;
    };

    u16* rd = smem;
    u16* md = smem + TILE;
    u16* pf = smem + 2 * TILE;
    STAGE(rd);
    STAGE(md);
    const int NS = K >> 6;

    for (int k = 0; k < NS - 1; k++) {
        if constexpr (G == 4) asm volatile("s_waitcnt vmcnt(4)" ::: "memory");
        else if constexpr (G == 6) asm volatile("s_waitcnt vmcnt(6)" ::: "memory");
        else asm volatile("s_waitcnt vmcnt(8)" ::: "memory");
        __builtin_amdgcn_s_barrier();
        bf16x8 a0[AI], a1[AI], b0[4], b1[4];
#pragma unroll
        for (int i = 0; i < AI; i++) {
            const u16* p = rd + (wmR + i * 16 + mr) * 64;
            a0[i] = *(const bf16x8*)(p + sw0);
            a1[i] = *(const bf16x8*)(p + sw1);
        }
#pragma unroll
        for (int j = 0; j < 4; j++) {
            const u16* p = rd + BMT * 64 + (wn * 64 + j * 16 + mr) * 64;
            b0[j] = *(const bf16x8*)(p + sw0);
            b1[j] = *(const bf16x8*)(p + sw1);
        }
        WAITL0;
        __builtin_amdgcn_sched_barrier(0);
        if (k + 2 < NS) STAGE(pf);
#pragma unroll
        for (int i = 0; i < AI; i++)
#pragma unroll
            for (int j = 0; j < 4; j++) {
                acc[i][j] = __builtin_amdgcn_mfma_f32_16x16x32_bf16(a0[i], b0[j], acc[i][j], 0, 0, 0);
                acc[i][j] = __builtin_amdgcn_mfma_f32_16x16x32_bf16(a1[i], b1[j], acc[i][j], 0, 0, 0);
            }
        u16* t = rd; rd = md; md = pf; pf = t;
    }
    // peeled last step
    WAITV0;
    __builtin_amdgcn_s_barrier();
    {
        bf16x8 a0[AI], a1[AI], b0[4], b1[4];
#pragma unroll
        for (int i = 0; i < AI; i++) {
            const u16* p = rd + (wmR + i * 16 + mr) * 64;
            a0[i] = *(const bf16x8*)(p + sw0);
            a1[i] = *(const bf16x8*)(p + sw1);
        }
#pragma unroll
        for (int j = 0; j < 4; j++) {
            const u16* p = rd + BMT * 64 + (wn * 64 + j * 16 + mr) * 64;
            b0[j] = *(const bf16x8*)(p + sw0);
            b1[j] = *(const bf16x8*)(p + sw1);
        }
#pragma unroll
        for (int i = 0; i < AI; i++)
#pragma unroll
            for (int j = 0; j < 4; j++) {
                acc[i][j] = __builtin_amdgcn_mfma_f32_16x16x32_bf16(a0[i], b0[j], acc[i][j], 0, 0, 0);
                acc[i][j] = __builtin_amdgcn_mfma_f32_16x16x32_bf16(a1[i], b1[j], acc[i][j], 0, 0, 0);
            }
    }
    __syncthreads();

    // ---- epilogue: LDS re-tile to coalesced stores ----
    float* ep = (float*)smem + wave * 1024;        // 16x64 f32, per-wave
    const int lq = lane >> 4, lmr = lane & 15;
    const int colb = n0 + wn * 64 + lmr * 4;
    float4 b4 = make_float4(0.f, 0.f, 0.f, 0.f);
    if (bias) b4 = *(const float4*)(bias + colb);
#pragma unroll
    for (int i = 0; i < AI; i++) {
#pragma unroll
        for (int j = 0; j < 4; j++)
#pragma unroll
            for (int r = 0; r < 4; r++)
                ep[(q * 4 + r) * 64 + j * 16 + mr] = acc[i][j][r];
        __syncthreads();
#pragma unroll
        for (int p = 0; p < 4; p++) {
            const int lr = p * 4 + lq;
            float4 v = *(const float4*)(ep + lr * 64 + lmr * 4);
            v.x += b4.x; v.y += b4.y; v.z += b4.z; v.w += b4.w;
            if (relu) {
                v.x = fmaxf(v.x, 0.f); v.y = fmaxf(v.y, 0.f);
                v.z = fmaxf(v.z, 0.f); v.w = fmaxf(v.w, 0.f);
            }
            uint2 pk;
            pk.x = (uint32_t)f2b(v.x) | ((uint32_t)f2b(v.y) << 16);
            pk.y = (uint32_t)f2b(v.z) | ((uint32_t)f2b(v.w) << 16);
            const int row = m0 + wm * WM + i * 16 + lr;
            *(uint2*)(Cb + (size_t)row * ldc + colb) = pk;
        }
        __syncthreads();
    }
}

// ============ logits GEMM: fp32 out + bias + replacement mask ============
// 128x128 tile, BK=32, 3-buffer depth-2 counted-vmcnt pipeline (G=4).
// LDS rows are 64 B (4 x 16 B chunks) swizzled: chunk c at c ^ ((row>>1)&3),
// applied via pre-swizzled global source; fragment reads 2-way conflict-free.
__global__ __launch_bounds__(256) void gemm_logits_mfma(
    const u16* __restrict__ A, const u16* __restrict__ BT,
    const float* __restrict__ bias, const int* __restrict__ fo,
    float* __restrict__ C, int K)
{
    constexpr int TILE = 256 * 32;
    __shared__ __align__(16) u16 smem[3 * TILE];
    const int tid = threadIdx.x;
    const int wave = tid >> 6, lane = tid & 63;
    const int m0 = blockIdx.y * 128, n0 = blockIdx.x * 128;

    const int srow = wave * 16 + (lane >> 2);
    const int scol = ((lane & 3) ^ ((lane >> 3) & 3)) * 8;   // pre-swizzled source col
    const u16* Ap  = A  + (size_t)(m0 + srow) * K + scol;
    const u16* Bp  = BT + (size_t)(n0 + srow) * K + scol;
    const u16* Ap2 = Ap + (size_t)64 * K;
    const u16* Bp2 = Bp + (size_t)64 * K;
    const int aW = wave * 16 * 32;
    const int bW = 128 * 32 + wave * 16 * 32;

    const int wm = wave >> 1, wn = wave & 1;
    const int q = lane >> 4, mr = lane & 15;
    const int swz = (q ^ ((mr >> 1) & 3)) * 8;               // swizzled chunk offset
    const int aRd = (wm * 64 + mr) * 32 + swz;
    const int bRd = 128 * 32 + (wn * 64 + mr) * 32 + swz;

    f32x4 acc[4][4];
    const f32x4 z = {0.f, 0.f, 0.f, 0.f};
#pragma unroll
    for (int i = 0; i < 4; i++)
#pragma unroll
        for (int j = 0; j < 4; j++) acc[i][j] = z;

#define STAGE4(buf) do { \
        GLL(Ap,  (buf) + aW); \
        GLL(Ap2, (buf) + aW + 64 * 32); \
        GLL(Bp,  (buf) + bW); \
        GLL(Bp2, (buf) + bW + 64 * 32); \
        Ap += 32; Ap2 += 32; Bp += 32; Bp2 += 32; \
    } while (0)

    u16* rd = smem;
    u16* md = smem + TILE;
    u16* pf = smem + 2 * TILE;
    STAGE4(rd);
    STAGE4(md);
    const int NS = K >> 5;

    for (int k = 0; k < NS - 1; k++) {
        WAITV4;
        __builtin_amdgcn_s_barrier();
        bf16x8 af[4], bfr[4];
#pragma unroll
        for (int i = 0; i < 4; i++) af[i]  = *(const bf16x8*)(rd + aRd + i * 16 * 32);
#pragma unroll
        for (int j = 0; j < 4; j++) bfr[j] = *(const bf16x8*)(rd + bRd + j * 16 * 32);
        WAITL0;
        __builtin_amdgcn_sched_barrier(0);
        if (k + 2 < NS) STAGE4(pf);
#pragma unroll
        for (int i = 0; i < 4; i++)
#pragma unroll
            for (int j = 0; j < 4; j++)
                acc[i][j] = __builtin_amdgcn_mfma_f32_16x16x32_bf16(af[i], bfr[j], acc[i][j], 0, 0, 0);
        u16* t = rd; rd = md; md = pf; pf = t;
    }
    WAITV0;
    __builtin_amdgcn_s_barrier();
    {
        bf16x8 af[4], bfr[4];
#pragma unroll
        for (int i = 0; i < 4; i++) af[i]  = *(const bf16x8*)(rd + aRd + i * 16 * 32);
#pragma unroll
        for (int j = 0; j < 4; j++) bfr[j] = *(const bf16x8*)(rd + bRd + j * 16 * 32);
#pragma unroll
        for (int i = 0; i < 4; i++)
#pragma unroll
            for (int j = 0; j < 4; j++)
                acc[i][j] = __builtin_amdgcn_mfma_f32_16x16x32_bf16(af[i], bfr[j], acc[i][j], 0, 0, 0);
    }
    __syncthreads();
#undef STAGE4

    float* ep = (float*)smem + wave * 1024;
    const int lq = lane >> 4, lmr = lane & 15;
    const int colb = n0 + wn * 64 + lmr * 4;
    const float4 b4 = *(const float4*)(bias + colb);
#pragma unroll
    for (int i = 0; i < 4; i++) {
#pragma unroll
        for (int j = 0; j < 4; j++)
#pragma unroll
            for (int r = 0; r < 4; r++)
                ep[(q * 4 + r) * 64 + j * 16 + mr] = acc[i][j][r];
        __syncthreads();
#pragma unroll
        for (int p = 0; p < 4; p++) {
            const int lr = p * 4 + lq;
            const int row = m0 + wm * 64 + i * 16 + lr;
            const int b = row >> 6, pos = row & 63;
            float4 v = *(const float4*)(ep + lr * 64 + lmr * 4);
            const int4 f4 = *(const int4*)(fo + (size_t)b * VV + colb);
            v.x = (f4.x <= pos) ? MASK_SENTINEL : v.x + b4.x;
            v.y = (f4.y <= pos) ? MASK_SENTINEL : v.y + b4.y;
            v.z = (f4.z <= pos) ? MASK_SENTINEL : v.z + b4.z;
            v.w = (f4.w <= pos) ? MASK_SENTINEL : v.w + b4.w;
            *(float4*)(C + (size_t)row * VV + colb) = v;
        }
        __syncthreads();
    }
}

// ============ batched 512x512 transpose+convert of the 8 per-layer weights ============
struct TPB {
    const float* s[8];
    u16* d[8];
    long dz[8];
};

__global__ __launch_bounds__(256) void transpose8_kernel(TPB t)
{
    __shared__ float tl[32][33];
    const int zz = blockIdx.z;          // m*6 + l
    const int m = zz / 6, l = zz - m * 6;
    const float* in = t.s[m] + (size_t)l * 262144;
    u16* out = t.d[m] + (size_t)l * t.dz[m];
    const int r0 = blockIdx.y * 32, c0 = blockIdx.x * 32;
    const int tx = threadIdx.x & 31, ty = threadIdx.x >> 5;
#pragma unroll
    for (int i = 0; i < 4; i++)
        tl[ty + 8 * i][tx] = in[(size_t)(r0 + ty + 8 * i) * 512 + c0 + tx];
    __syncthreads();
#pragma unroll
    for (int i = 0; i < 4; i++)
        out[(size_t)(c0 + ty + 8 * i) * 512 + r0 + tx] = f2b(tl[tx][ty + 8 * i]);
}

// ============ generic transpose + fp32->bf16: in[R][C] -> out[C][R] ============
__global__ __launch_bounds__(256) void transpose_bf16_kernel(
    const float* __restrict__ in, u16* __restrict__ out,
    int R, int C, size_t in_z, size_t out_z)
{
    __shared__ float tl[32][33];
    in  += (size_t)blockIdx.z * in_z;
    out += (size_t)blockIdx.z * out_z;
    const int r0 = blockIdx.y * 32, c0 = blockIdx.x * 32;
    const int tx = threadIdx.x & 31, ty = threadIdx.x >> 5;
#pragma unroll
    for (int i = 0; i < 4; i++)
        tl[ty + 8 * i][tx] = in[(size_t)(r0 + ty + 8 * i) * C + c0 + tx];
    __syncthreads();
#pragma unroll
    for (int i = 0; i < 4; i++)
        out[(size_t)(c0 + ty + 8 * i) * R + r0 + tx] = f2b(tl[tx][ty + 8 * i]);
}

// ============ fp32 -> bf16 convert ============
__global__ __launch_bounds__(256) void convert_bf16_kernel(
    const float* __restrict__ in, u16* __restrict__ out)
{
    const int idx = blockIdx.x * 256 + threadIdx.x;
    float4 v = *reinterpret_cast<const float4*>(in + (size_t)idx * 4);
    uint2 p;
    p.x = (uint32_t)f2b(v.x) | ((uint32_t)f2b(v.y) << 16);
    p.y = (uint32_t)f2b(v.z) | ((uint32_t)f2b(v.w) << 16);
    *reinterpret_cast<uint2*>(out + (size_t)idx * 4) = p;
}

// ============ attention: bf16 q/k/v in, bf16 out; one block per (b,h) ============
__global__ __launch_bounds__(256) void attn_kernel(
    const u16* __restrict__ qg, int qld,
    const u16* __restrict__ kg, const u16* __restrict__ vg, int kvld,
    u16* __restrict__ og, int causal)
{
    __shared__ float qs[SS][68];
    __shared__ float ks[SS][68];
    __shared__ float vs[SS][68];
    __shared__ float red[SS][8];
    float (*ps)[68] = qs;

    const int tid = threadIdx.x;
    const int bh = blockIdx.x;
    const int b = bh >> 3, h = bh & 7;
    const size_t qbase = (size_t)b * SS * qld + (size_t)h * DH;
    const size_t kbase = (size_t)b * SS * kvld + (size_t)h * DH;
    const size_t obase = (size_t)b * SS * DM + (size_t)h * DH;

#pragma unroll
    for (int it = 0; it < 4; it++) {
        int idx = tid + 256 * it;          // 0..1023
        int s = idx >> 4;
        int d4 = (idx & 15) << 2;
        uint2 a = *(const uint2*)(qg + qbase + (size_t)s * qld + d4);
        qs[s][d4 + 0] = blo(a.x); qs[s][d4 + 1] = bhi(a.x);
        qs[s][d4 + 2] = blo(a.y); qs[s][d4 + 3] = bhi(a.y);
        uint2 c = *(const uint2*)(kg + kbase + (size_t)s * kvld + d4);
        ks[s][d4 + 0] = blo(c.x); ks[s][d4 + 1] = bhi(c.x);
        ks[s][d4 + 2] = blo(c.y); ks[s][d4 + 3] = bhi(c.y);
        uint2 e = *(const uint2*)(vg + kbase + (size_t)s * kvld + d4);
        vs[s][d4 + 0] = blo(e.x); vs[s][d4 + 1] = bhi(e.x);
        vs[s][d4 + 2] = blo(e.y); vs[s][d4 + 3] = bhi(e.y);
    }
    __syncthreads();

    const int r = tid >> 2, c = tid & 3;

    float sc[16];
#pragma unroll
    for (int jj = 0; jj < 16; jj++) sc[jj] = 0.f;
    for (int d4 = 0; d4 < 64; d4 += 4) {
        float4 qv = *reinterpret_cast<const float4*>(&qs[r][d4]);
#pragma unroll
        for (int jj = 0; jj < 16; jj++) {
            int j = jj * 4 + c;
            float4 kv = *reinterpret_cast<const float4*>(&ks[j][d4]);
            sc[jj] += qv.x * kv.x + qv.y * kv.y + qv.z * kv.z + qv.w * kv.w;
        }
    }
    float mx = -1e30f;
#pragma unroll
    for (int jj = 0; jj < 16; jj++) {
        int j = jj * 4 + c;
        float s_ = sc[jj] * 0.125f;
        if (causal && j > r) s_ = -1e9f;
        sc[jj] = s_;
        mx = fmaxf(mx, s_);
    }
    red[r][c] = mx;
    __syncthreads();
    float m = fmaxf(fmaxf(red[r][0], red[r][1]), fmaxf(red[r][2], red[r][3]));
    float sum = 0.f;
#pragma unroll
    for (int jj = 0; jj < 16; jj++) {
        float p = expf(sc[jj] - m);
        sc[jj] = p;
        sum += p;
    }
    red[r][4 + c] = sum;
    __syncthreads();
    float tot = red[r][4] + red[r][5] + red[r][6] + red[r][7];
    float inv = 1.f / tot;
#pragma unroll
    for (int jj = 0; jj < 16; jj++) ps[r][jj * 4 + c] = sc[jj] * inv;
    __syncthreads();

    float acc[16];
#pragma unroll
    for (int i = 0; i < 16; i++) acc[i] = 0.f;
    for (int j = 0; j < 64; j++) {
        float pj = ps[r][j];
#pragma unroll
        for (int dd = 0; dd < 4; dd++) {
            float4 vv = *reinterpret_cast<const float4*>(&vs[j][c * 16 + dd * 4]);
            acc[dd * 4 + 0] += pj * vv.x;
            acc[dd * 4 + 1] += pj * vv.y;
            acc[dd * 4 + 2] += pj * vv.z;
            acc[dd * 4 + 3] += pj * vv.w;
        }
    }
#pragma unroll
    for (int dd = 0; dd < 4; dd++) {
        uint2 p;
        p.x = (uint32_t)f2b(acc[dd * 4 + 0]) | ((uint32_t)f2b(acc[dd * 4 + 1]) << 16);
        p.y = (uint32_t)f2b(acc[dd * 4 + 2]) | ((uint32_t)f2b(acc[dd * 4 + 3]) << 16);
        *reinterpret_cast<uint2*>(&og[obase + (size_t)r * DM + c * 16 + dd * 4]) = p;
    }
}

// ============ residual add + layernorm; x fp32, proj bf16; writes fp32 + bf16 ============
__global__ __launch_bounds__(256) void add_ln_kernel(
    const float* __restrict__ x, const u16* __restrict__ a,
    const float* __restrict__ g, const float* __restrict__ be,
    float* __restrict__ y, u16* __restrict__ yb)
{
    const int wave = threadIdx.x >> 6, lane = threadIdx.x & 63;
    const int row = blockIdx.x * 4 + wave;
    const float* xr = x + (size_t)row * DM;
    const u16* ar = a + (size_t)row * DM;
    float* yr = y + (size_t)row * DM;
    u16* ybr = yb + (size_t)row * DM;

    float vbuf[8];
    float sum = 0.f, sq = 0.f;
#pragma unroll
    for (int i = 0; i < 2; i++) {
        int d = lane * 8 + i * 4;
        float4 xv = *reinterpret_cast<const float4*>(&xr[d]);
        uint2 av = *(const uint2*)(ar + d);
        float a0 = blo(av.x), a1 = bhi(av.x), a2 = blo(av.y), a3 = bhi(av.y);
        float v0 = xv.x + a0, v1 = xv.y + a1, v2 = xv.z + a2, v3 = xv.w + a3;
        vbuf[i * 4 + 0] = v0; vbuf[i * 4 + 1] = v1;
        vbuf[i * 4 + 2] = v2; vbuf[i * 4 + 3] = v3;
        sum += v0 + v1 + v2 + v3;
        sq += v0 * v0 + v1 * v1 + v2 * v2 + v3 * v3;
    }
#pragma unroll
    for (int off = 32; off; off >>= 1) {
        sum += __shfl_xor(sum, off, 64);
        sq  += __shfl_xor(sq, off, 64);
    }
    float mean = sum * (1.f / 512.f);
    float var = sq * (1.f / 512.f) - mean * mean;
    float rs = rsqrtf(var + 1e-3f);
#pragma unroll
    for (int i = 0; i < 2; i++) {
        int d = lane * 8 + i * 4;
        float4 gv = *reinterpret_cast<const float4*>(&g[d]);
        float4 bv = *reinterpret_cast<const float4*>(&be[d]);
        float4 ov;
        ov.x = (vbuf[i * 4 + 0] - mean) * rs * gv.x + bv.x;
        ov.y = (vbuf[i * 4 + 1] - mean) * rs * gv.y + bv.y;
        ov.z = (vbuf[i * 4 + 2] - mean) * rs * gv.z + bv.z;
        ov.w = (vbuf[i * 4 + 3] - mean) * rs * gv.w + bv.w;
        *reinterpret_cast<float4*>(&yr[d]) = ov;
        uint2 p;
        p.x = (uint32_t)f2b(ov.x) | ((uint32_t)f2b(ov.y) << 16);
        p.y = (uint32_t)f2b(ov.z) | ((uint32_t)f2b(ov.w) << 16);
        *reinterpret_cast<uint2*>(&ybr[d]) = p;
    }
}

// ============ embedding; writes fp32 + bf16 ============
__global__ __launch_bounds__(256) void embed_kernel(
    const int* __restrict__ targets, const float* __restrict__ tok,
    const float* __restrict__ pos, float* __restrict__ x, u16* __restrict__ xb)
{
    int idx = blockIdx.x * 256 + threadIdx.x;
    int row = idx >> 7;
    int d4 = (idx & 127) << 2;
    int s = row & 63;
    int t = targets[row];
    float4 tv = *reinterpret_cast<const float4*>(&tok[(size_t)t * DM + d4]);
    float4 pv = *reinterpret_cast<const float4*>(&pos[(size_t)s * DM + d4]);
    float4 ov = make_float4(tv.x + pv.x, tv.y + pv.y, tv.z + pv.z, tv.w + pv.w);
    *reinterpret_cast<float4*>(&x[(size_t)row * DM + d4]) = ov;
    uint2 p;
    p.x = (uint32_t)f2b(ov.x) | ((uint32_t)f2b(ov.y) << 16);
    p.y = (uint32_t)f2b(ov.z) | ((uint32_t)f2b(ov.w) << 16);
    *reinterpret_cast<uint2*>(&xb[(size_t)row * DM + d4]) = p;
}

// ============ replacement-mask first-occurrence ============
__global__ __launch_bounds__(256) void init_fo_kernel(int* __restrict__ fo)
{
    fo[blockIdx.x * 256 + threadIdx.x] = SS;
}

__global__ __launch_bounds__(256) void scatter_fo_kernel(
    const int* __restrict__ targets, int* __restrict__ fo)
{
    int i = blockIdx.x * 256 + threadIdx.x;
    int t = targets[i];
    if (t != 0) atomicMin(&fo[(size_t)(i >> 6) * VV + t], i & 63);
}

// ============ launch ============
extern "C" void kernel_launch(void* const* d_in, const int* in_sizes, int n_in,
                              void* d_out, int out_size, void* d_ws, size_t ws_size,
                              hipStream_t stream)
{
    const float* enc_feat = (const float*)d_in[0];
    const int*   targets  = (const int*)d_in[1];
    const float* conv_w   = (const float*)d_in[2];
    const float* conv_b   = (const float*)d_in[3];
    const float* tok_emb  = (const float*)d_in[4];
    const float* pos_emb  = (const float*)d_in[5];
    const float* Wq_s     = (const float*)d_in[6];
    const float* Wk_s     = (const float*)d_in[7];
    const float* Wv_s     = (const float*)d_in[8];
    const float* Wo_s     = (const float*)d_in[9];
    const float* Wq_c     = (const float*)d_in[10];
    const float* Wk_c     = (const float*)d_in[11];
    const float* Wv_c     = (const float*)d_in[12];
    const float* Wo_c     = (const float*)d_in[13];
    const float* W1       = (const float*)d_in[14];
    const float* fb1      = (const float*)d_in[15];
    const float* W2       = (const float*)d_in[16];
    const float* fb2      = (const float*)d_in[17];
    const float* g1       = (const float*)d_in[18];
    const float* be1      = (const float*)d_in[19];
    const float* g2       = (const float*)d_in[20];
    const float* be2      = (const float*)d_in[21];
    const float* g3       = (const float*)d_in[22];
    const float* be3      = (const float*)d_in[23];
    const float* Wout     = (const float*)d_in[24];
    const float* bout     = (const float*)d_in[25];
    float* out = (float*)d_out;

    // ---- workspace layout (u16 units from base; ~160 MB total, ws = 512 MB) ----
    u16* base = (u16*)d_ws;
    float* x   = (float*)d_ws;                 // 4096x512 f32 (residual)
    u16* xb    = base + 4194304;               // 4096x512 bf16
    u16* projb = base + 6291456;               // 4096x512 bf16
    u16* qcb   = base + 8388608;               // 4096x512 bf16 (cross Q)
    u16* attnb = base + 10485760;              // 4096x512 bf16
    u16* encb  = base + 12582912;              // 4096x512 bf16
    u16* big   = base + 14680064;              // 4096x2048 bf16 (qkv | ffn-h | enc_feat)
    int* fo    = (int*)(base + 23068672);      // 64x8192 int
    u16* qkvT  = base + 24117248;              // [6][1536][512]
    u16* woTs  = base + 28835840;              // [6][512][512]
    u16* wqTc  = base + 30408704;              // [6][512][512]
    u16* kvTc  = base + 31981568;              // [6][1024][512] (contiguous => [6144][512])
    u16* woTc  = base + 35127296;              // [6][512][512]
    u16* w1T   = base + 36700160;              // [6][2048][512]
    u16* w2T   = base + 42991616;              // [6][512][2048]
    u16* cvT   = base + 49283072;              // [512][2048]
    u16* woutT = base + 50331648;              // [8192][512]
    u16* kvAll = base + 54525952;              // [4096][6144] bf16: all-layer cross K|V

    const dim3 blk(256);

    // ---- mask precompute + embedding + enc_feat conversion ----
    init_fo_kernel<<<dim3(BB * VV / 256), blk, 0, stream>>>(fo);
    scatter_fo_kernel<<<dim3(MR / 256), blk, 0, stream>>>(targets, fo);
    embed_kernel<<<dim3(MR * DM / 4 / 256), blk, 0, stream>>>(targets, tok_emb, pos_emb, x, xb);
    convert_bf16_kernel<<<dim3(MR * ENCC / 4 / 256), blk, 0, stream>>>(enc_feat, big);

    // ---- weight transpose+convert ----
    TPB tp;
    tp.s[0] = Wq_s; tp.d[0] = qkvT;          tp.dz[0] = 786432;
    tp.s[1] = Wk_s; tp.d[1] = qkvT + 262144; tp.dz[1] = 786432;
    tp.s[2] = Wv_s; tp.d[2] = qkvT + 524288; tp.dz[2] = 786432;
    tp.s[3] = Wo_s; tp.d[3] = woTs;          tp.dz[3] = 262144;
    tp.s[4] = Wq_c; tp.d[4] = wqTc;          tp.dz[4] = 262144;
    tp.s[5] = Wk_c; tp.d[5] = kvTc;          tp.dz[5] = 524288;
    tp.s[6] = Wv_c; tp.d[6] = kvTc + 262144; tp.dz[6] = 524288;
    tp.s[7] = Wo_c; tp.d[7] = woTc;          tp.dz[7] = 262144;
    transpose8_kernel<<<dim3(16, 16, 48), blk, 0, stream>>>(tp);
    transpose_bf16_kernel<<<dim3(64, 16, 6), blk, 0, stream>>>(W1, w1T, 512, 2048, 1048576, 1048576);
    transpose_bf16_kernel<<<dim3(16, 64, 6), blk, 0, stream>>>(W2, w2T, 2048, 512, 1048576, 1048576);
    transpose_bf16_kernel<<<dim3(16, 64, 1), blk, 0, stream>>>(conv_w, cvT, 2048, 512, 0, 0);
    transpose_bf16_kernel<<<dim3(256, 16, 1), blk, 0, stream>>>(Wout, woutT, 512, 8192, 0, 0);

    // ---- encoder projection: big(enc_feat bf16) @ cvT + conv_b -> encb ----
    gemm_bf16<64, 64><<<dim3(8, 64), blk, 0, stream>>>(big, cvT, conv_b, encb, ENCC, DM, 0);

    // ---- hoisted cross-attention K|V for ALL layers: encb @ kvTc^T -> kvAll ----
    gemm_bf16<64, 128><<<dim3(48, 64), blk, 0, stream>>>(encb, kvTc, nullptr, kvAll, DM, 6144, 0);

    for (int l = 0; l < LL; l++) {
        // self-attention: fused QKV -> big[4096][1536]
        gemm_bf16<64, 128><<<dim3(12, 64), blk, 0, stream>>>(xb, qkvT + (size_t)l * 786432, nullptr,
                                                             big, DM, 1536, 0);
        attn_kernel<<<dim3(BB * NH), blk, 0, stream>>>(big, 1536, big + 512, big + 1024, 1536, attnb, 1);
        gemm_bf16<64, 64><<<dim3(8, 64), blk, 0, stream>>>(attnb, woTs + (size_t)l * 262144, nullptr,
                                                           projb, DM, DM, 0);
        add_ln_kernel<<<dim3(MR / 4), blk, 0, stream>>>(x, projb, g1 + l * DM, be1 + l * DM, x, xb);
        // cross-attention: Q projection only (KV hoisted to kvAll)
        gemm_bf16<64, 64><<<dim3(8, 64), blk, 0, stream>>>(xb, wqTc + (size_t)l * 262144, nullptr,
                                                           qcb, DM, DM, 0);
        attn_kernel<<<dim3(BB * NH), blk, 0, stream>>>(qcb, 512,
                                                       kvAll + (size_t)l * 1024,
                                                       kvAll + (size_t)l * 1024 + 512, 6144, attnb, 0);
        gemm_bf16<64, 64><<<dim3(8, 64), blk, 0, stream>>>(attnb, woTc + (size_t)l * 262144, nullptr,
                                                           projb, DM, DM, 0);
        add_ln_kernel<<<dim3(MR / 4), blk, 0, stream>>>(x, projb, g2 + l * DM, be2 + l * DM, x, xb);
        // FFN
        gemm_bf16<64, 128><<<dim3(16, 64), blk, 0, stream>>>(xb, w1T + (size_t)l * 1048576,
                                                             fb1 + (size_t)l * FF, big, DM, FF, 1);
        gemm_bf16<64, 64><<<dim3(8, 64), blk, 0, stream>>>(big, w2T + (size_t)l * 1048576,
                                                           fb2 + (size_t)l * DM, projb, FF, DM, 0);
        add_ln_kernel<<<dim3(MR / 4), blk, 0, stream>>>(x, projb, g3 + l * DM, be3 + l * DM, x, xb);
    }

    // logits + bias + replacement mask
    gemm_logits_mfma<<<dim3(64, 32), blk, 0, stream>>>(xb, woutT, bout, fo, out, DM);
}